// Round 2
// baseline (655.187 us; speedup 1.0000x reference)
//
#include <hip/hip_runtime.h>
#include <cstdint>
#include <cstddef>

// MI355X / gfx950. bf16 MFMA implementation of ConditionalCrossAttention.
// score = (qc+qp)|(qc+qp+qs)  dot  kc|kp   (algebraic refold of the concat heads)
// R6: key-side projection FUSED into attention. Each attn block computes its
// (batch,head) K-tile (kc|kp) and V-tile on the fly from key/key_pos/value with
// a per-head 48KB bf16 W slice (double-buffered 12KB quarter staging), writing
// straight into the swizzled Ks/Vt LDS tiles. Eliminates the 96MB K/V HBM
// round-trip and the key_side kernel + its serialization (~125us + ~180MB W).

typedef float  f4  __attribute__((ext_vector_type(4)));
typedef __bf16 b8v __attribute__((ext_vector_type(8)));

#define MFMA_BF16(a, b, c) __builtin_amdgcn_mfma_f32_16x16x32_bf16((a), (b), (c), 0, 0, 0)

#define GLD_LDS16(gp, lp)                                             \
  __builtin_amdgcn_global_load_lds(                                   \
      (const __attribute__((address_space(1))) void*)(gp),            \
      (__attribute__((address_space(3))) void*)(lp), 16, 0, 0)

// ---------------------------------------------------------------------------
// Prepass: build per-head weight slices, fp32 -> bf16.
// Wslice[h][j][k]: j in [0,32) -> W_kc[h*32+j][k]; [32,64) -> W_kp; [64,96) -> W_v.
__global__ __launch_bounds__(256) void convert_w(
    const float* __restrict__ W_kc, const float* __restrict__ W_kp,
    const float* __restrict__ W_v, __bf16* __restrict__ Wslice)
{
  int i = blockIdx.x * 256 + threadIdx.x;      // 0 .. 49151
  int base = i * 4;                            // elem index into [8][96][256]
  int h = base / 24576;
  int rem = base - h * 24576;
  int j = rem >> 8;                            // 0..95
  int k = rem & 255;
  const float* W = (j < 32) ? W_kc : (j < 64) ? W_kp : W_v;
  int r = j & 31;
  float4 v = *(const float4*)(W + (size_t)(h * 32 + r) * 256 + k);
  __bf16 o[4];
  o[0] = (__bf16)v.x; o[1] = (__bf16)v.y; o[2] = (__bf16)v.z; o[3] = (__bf16)v.w;
  *(uint2*)(Wslice + base) = *(uint2*)o;
}

// ---------------------------------------------------------------------------
// Kernel B: query-side (unchanged).
__global__ __launch_bounds__(256) void query_side_gemm(
    const float* __restrict__ query, const float* __restrict__ query_pos,
    const float* __restrict__ query_sine,
    const float* __restrict__ W_qc, const float* __restrict__ b_qc,
    const float* __restrict__ W_qp, const float* __restrict__ b_qp,
    const float* __restrict__ W_qs, const float* __restrict__ b_qs,
    __bf16* __restrict__ Q64)
{
  __shared__ __bf16 Ws[256][72];
  const int tid  = threadIdx.x;
  const int wave = tid >> 6, lane = tid & 63;
  const int lrow = lane & 15, quad = lane >> 4;
  const int r0 = blockIdx.x * 64;

  f4 acc[16];
#pragma unroll
  for (int i = 0; i < 16; ++i) acc[i] = f4{0.f, 0.f, 0.f, 0.f};

  for (int kc = 0; kc < 768; kc += 64) {
    const float* X; const float* W;
    if (kc < 256)      { X = query;      W = W_qc; }
    else if (kc < 512) { X = query_pos;  W = W_qp; }
    else               { X = query_sine; W = W_qs; }
    const int ko = kc & 255;
#pragma unroll
    for (int it = 0; it < 16; ++it) {
      int idx = it * 256 + tid;
      int row = idx >> 4, c4 = idx & 15;
      float4 w = *(const float4*)(W + (size_t)row * 256 + ko + c4 * 4);
      __bf16* dp = &Ws[row][c4 * 4];
      dp[0] = (__bf16)w.x; dp[1] = (__bf16)w.y; dp[2] = (__bf16)w.z; dp[3] = (__bf16)w.w;
    }
    __syncthreads();
#pragma unroll
    for (int kk = 0; kk < 64; kk += 32) {
      const float* xp = X + (size_t)(r0 + wave * 16 + lrow) * 256 + ko + kk + quad * 8;
      float4 x0 = *(const float4*)xp;
      float4 x1 = *(const float4*)(xp + 4);
      b8v a;
      a[0] = (__bf16)x0.x; a[1] = (__bf16)x0.y; a[2] = (__bf16)x0.z; a[3] = (__bf16)x0.w;
      a[4] = (__bf16)x1.x; a[5] = (__bf16)x1.y; a[6] = (__bf16)x1.z; a[7] = (__bf16)x1.w;
#pragma unroll
      for (int ct = 0; ct < 16; ++ct) {
        b8v bf = *(const b8v*)&Ws[ct * 16 + lrow][kk + quad * 8];
        acc[ct] = MFMA_BF16(a, bf, acc[ct]);
      }
    }
    __syncthreads();
    if (kc == 448) {
#pragma unroll
      for (int ct = 0; ct < 16; ++ct) {
        int col = ct * 16 + lrow;
        float bsum = b_qc[col] + b_qp[col];
        int h = col >> 5, d = col & 31;
#pragma unroll
        for (int r = 0; r < 4; ++r) {
          int row = r0 + wave * 16 + quad * 4 + r;
          int n = row >> 4, bb = row & 15;
          Q64[((size_t)(bb * 8 + h) * 320 + n) * 64 + d] = (__bf16)((acc[ct][r] + bsum) * 0.125f);
        }
      }
    }
  }
#pragma unroll
  for (int ct = 0; ct < 16; ++ct) {
    int col = ct * 16 + lrow;
    float bsum = b_qc[col] + b_qp[col] + b_qs[col];
    int h = col >> 5, d = col & 31;
#pragma unroll
    for (int r = 0; r < 4; ++r) {
      int row = r0 + wave * 16 + quad * 4 + r;
      int n = row >> 4, bb = row & 15;
      Q64[((size_t)(bb * 8 + h) * 320 + n) * 64 + 32 + d] = (__bf16)((acc[ct][r] + bsum) * 0.125f);
    }
  }
}

// ---------------------------------------------------------------------------
// Kernel C v6: fused projection + flash attention, L-split.
// Grid (4 ls, 128 bh), 256 threads. Per chunk of 128 tokens:
//   proj: Ks[l][0:32]=key.Wkc+b, Ks[l][32:64]=key_pos.Wkp+b, Vt=value.Wv+b
//         (3 sub-GEMMs, W quarters double-buffered in 2x12KB LDS)
//   attn: identical S^T-orientation compute as v4/v5 (Ks/Vt layouts unchanged).
__global__ __launch_bounds__(256, 2) void proj_attn(
    const float* __restrict__ key, const float* __restrict__ key_pos,
    const float* __restrict__ value, const __bf16* __restrict__ Wslice,
    const float* __restrict__ b_kc, const float* __restrict__ b_kp,
    const float* __restrict__ b_v,
    const __bf16* __restrict__ Q64,
    __bf16* __restrict__ Opart, float* __restrict__ Mpart, float* __restrict__ Lpart)
{
  __shared__ __bf16 Wsh[2][96 * 64];  // 24 KB, 2 x (96 rows x 64 k), xor-swizzled
  __shared__ __bf16 Ks[128 * 64];     // 16 KB, xor-swizzled 16B granules
  __shared__ __bf16 Vt[32][136];      // 8.5 KB, natural [d][l]
  __shared__ __bf16 Pt[4][16][136];   // 17.4 KB, per-wave P^T [q][l]
  const int tid  = threadIdx.x;
  const int wave = tid >> 6, lane = tid & 63;
  const int lrow = lane & 15, quad = lane >> 4;
  const int ls = blockIdx.x, bh = blockIdx.y;
  const int batch = bh >> 3, h = bh & 7;
  const int l0base = ls * 1024;

  const __bf16* __restrict__ Wb = Wslice + (size_t)h * 96 * 256;

  // Q fragments: 5 tiles of 16 q-rows per wave; serves as MFMA B operand.
  b8v qa0[5], qa1[5];
#pragma unroll
  for (int t = 0; t < 5; ++t) {
    const __bf16* Qb = Q64 + ((size_t)bh * 320 + wave * 80 + t * 16 + lrow) * 64;
    qa0[t] = *(const b8v*)(Qb + quad * 8);
    qa1[t] = *(const b8v*)(Qb + 32 + quad * 8);
  }

  // --- W quarter staging: 96 rows x 64 k (granule-XOR swizzled, linear LDS) ---
  auto stageW = [&](int qt, int buf) {
#pragma unroll
    for (int it = 0; it < 3; ++it) {
      int slot = it * 256 + tid;                 // 0..767 granules of 16B
      int j = slot >> 3, gp = slot & 7;
      int g = gp ^ (j & 7);
      GLD_LDS16(Wb + (size_t)j * 256 + qt * 64 + g * 8,
                (char*)&Wsh[buf][0] + slot * 16);
    }
  };
  auto readW = [&](int buf, int n, int G) -> b8v {   // row n (0..95), granule G (0..7)
    int gs = G ^ (n & 7);
    return *(const b8v*)((const char*)&Wsh[buf][0] + n * 128 + gs * 16);
  };
  auto mk = [&](float4 x0, float4 x1) -> b8v {
    b8v t;
    t[0] = (__bf16)x0.x; t[1] = (__bf16)x0.y; t[2] = (__bf16)x0.z; t[3] = (__bf16)x0.w;
    t[4] = (__bf16)x1.x; t[5] = (__bf16)x1.y; t[6] = (__bf16)x1.z; t[7] = (__bf16)x1.w;
    return t;
  };

  // projection accumulators: [m][row-tile][col-tile]
  f4 pacc[3][2][2];
#pragma unroll
  for (int m = 0; m < 3; ++m)
#pragma unroll
    for (int i = 0; i < 2; ++i)
#pragma unroll
      for (int j = 0; j < 2; ++j) pacc[m][i][j] = f4{0.f, 0.f, 0.f, 0.f};

  auto projq = [&](int c, int qt, int buf) {
#pragma unroll
    for (int m = 0; m < 3; ++m) {
      const float* __restrict__ X = (m == 0) ? key : (m == 1) ? key_pos : value;
#pragma unroll
      for (int ks = 0; ks < 2; ++ks) {
#pragma unroll
        for (int rt = 0; rt < 2; ++rt) {
          int row = l0base + c * 128 + wave * 32 + rt * 16 + lrow;
          const float* xp = X + ((size_t)row * 16 + batch) * 256
                              + qt * 64 + ks * 32 + quad * 8;
          float4 x0 = *(const float4*)xp;
          float4 x1 = *(const float4*)(xp + 4);
          b8v a = mk(x0, x1);
#pragma unroll
          for (int ct = 0; ct < 2; ++ct) {
            b8v bfr = readW(buf, m * 32 + ct * 16 + lrow, ks * 4 + quad);
            pacc[m][rt][ct] = MFMA_BF16(a, bfr, pacc[m][rt][ct]);
          }
        }
      }
    }
  };

  auto writeKsVt = [&]() {
#pragma unroll
    for (int m = 0; m < 3; ++m) {
      const float* __restrict__ bias = (m == 0) ? b_kc : (m == 1) ? b_kp : b_v;
#pragma unroll
      for (int ct = 0; ct < 2; ++ct) {
        int col = ct * 16 + lrow;
        float bv = bias[h * 32 + col];
#pragma unroll
        for (int rt = 0; rt < 2; ++rt) {
#pragma unroll
          for (int r = 0; r < 4; ++r) {
            int l = wave * 32 + rt * 16 + quad * 4 + r;
            float val = pacc[m][rt][ct][r] + bv;
            if (m < 2) {
              int glin = m * 4 + ct * 2 + (lrow >> 3);
              *((__bf16*)((char*)Ks + l * 128 + ((glin ^ (l & 7)) * 16) + (col & 7) * 2))
                  = (__bf16)val;
            } else {
              Vt[col][l] = (__bf16)val;
            }
          }
        }
        // reset for next chunk
#pragma unroll
        for (int rt = 0; rt < 2; ++rt) pacc[m][rt][ct] = f4{0.f, 0.f, 0.f, 0.f};
      }
    }
  };

  auto readKA = [&](int wr, int g) -> b8v {   // K[l=wr][c = g*8 .. +8]
    int gs = g ^ (wr & 7);
    return *(const b8v*)((const char*)Ks + wr * 128 + gs * 16);
  };

  float mst[5], lst[5];
  f4 oacc[5][2];
#pragma unroll
  for (int t = 0; t < 5; ++t) {
    mst[t] = -1e30f; lst[t] = 0.f;
    oacc[t][0] = f4{0.f, 0.f, 0.f, 0.f};
    oacc[t][1] = f4{0.f, 0.f, 0.f, 0.f};
  }

  auto compute = [&]() {
#pragma unroll
    for (int t = 0; t < 5; ++t) {
      // S^T tiles: row l = ct*16 + quad*4 + r, col q = lrow
      f4 sc[8];
#pragma unroll
      for (int ct = 0; ct < 8; ++ct) {
        b8v ka0 = readKA(ct * 16 + lrow, quad);
        b8v ka1 = readKA(ct * 16 + lrow, 4 + quad);
        f4 z = f4{0.f, 0.f, 0.f, 0.f};
        z = MFMA_BF16(ka0, qa0[t], z);
        z = MFMA_BF16(ka1, qa1[t], z);
        sc[ct] = z;
      }
      // softmax over l: in-lane (32 vals) + cross-quad (lane^16, lane^32)
      float mx = sc[0][0];
#pragma unroll
      for (int ct = 0; ct < 8; ++ct)
#pragma unroll
        for (int r = 0; r < 4; ++r) mx = fmaxf(mx, sc[ct][r]);
      mx = fmaxf(mx, __shfl_xor(mx, 16));
      mx = fmaxf(mx, __shfl_xor(mx, 32));
      float mnew = fmaxf(mst[t], mx);
      float alpha = __expf(mst[t] - mnew);
      mst[t] = mnew;
      float rsum = 0.f;
#pragma unroll
      for (int ct = 0; ct < 8; ++ct)
#pragma unroll
        for (int r = 0; r < 4; ++r) {
          sc[ct][r] = __expf(sc[ct][r] - mnew);
          rsum += sc[ct][r];
        }
      rsum += __shfl_xor(rsum, 16);
      rsum += __shfl_xor(rsum, 32);
      lst[t] = lst[t] * alpha + rsum;
#pragma unroll
      for (int c2 = 0; c2 < 2; ++c2)
#pragma unroll
        for (int r = 0; r < 4; ++r) oacc[t][c2][r] *= alpha;

      // P^T -> per-wave LDS [q=lrow][l]; b64 writes (4 consecutive l per reg)
#pragma unroll
      for (int ct = 0; ct < 8; ++ct) {
        __bf16 p4[4];
#pragma unroll
        for (int r = 0; r < 4; ++r) p4[r] = (__bf16)sc[ct][r];
        *(uint2*)&Pt[wave][lrow][ct * 16 + quad * 4] = *(const uint2*)p4;
      }
      // O^T += V^T P^T
#pragma unroll
      for (int kt = 0; kt < 4; ++kt) {
        b8v pb = *(const b8v*)&Pt[wave][lrow][kt * 32 + quad * 8];
#pragma unroll
        for (int c2 = 0; c2 < 2; ++c2) {
          b8v va = *(const b8v*)&Vt[c2 * 16 + lrow][kt * 32 + quad * 8];
          oacc[t][c2] = MFMA_BF16(va, pb, oacc[t][c2]);
        }
      }
    }
  };

  // ---- main loop: 8 chunks of 128 tokens ----
  stageW(0, 0);
  __syncthreads();
  for (int c = 0; c < 8; ++c) {
#pragma unroll
    for (int qt = 0; qt < 4; ++qt) {
      int buf = qt & 1;
      // prefetch next quarter (or next chunk's quarter 0 - same W) into other buf
      stageW((qt + 1) & 3, buf ^ 1);
      projq(c, qt, buf);
      __syncthreads();   // stage drained (vmcnt) + all waves done reading buf
    }
    writeKsVt();
    __syncthreads();     // Ks/Vt ready for all waves
    compute();
    __syncthreads();     // Ks/Vt reads done before next chunk's writeKsVt
  }

  // epilogue: O^T[d][q] -> Opart[q][d] (b64 packed), m/l per q
  const size_t pbase = ((size_t)bh * 4 + ls) * 320;
#pragma unroll
  for (int t = 0; t < 5; ++t) {
    int q = wave * 80 + t * 16 + lrow;
    float inv = 1.0f / lst[t];
#pragma unroll
    for (int c2 = 0; c2 < 2; ++c2) {
      __bf16 o4[4];
#pragma unroll
      for (int r = 0; r < 4; ++r) o4[r] = (__bf16)(oacc[t][c2][r] * inv);
      *(uint2*)&Opart[(pbase + q) * 32 + c2 * 16 + quad * 4] = *(const uint2*)o4;
    }
    if (quad == 0) {
      Mpart[pbase + q] = mst[t];
      Lpart[pbase + q] = lst[t];
    }
  }
}

// ---------------------------------------------------------------------------
// Kernel C2: combine 4 L-split partials -> Obf[b][n][256] (unchanged).
__global__ __launch_bounds__(256) void attn_combine(
    const __bf16* __restrict__ Opart, const float* __restrict__ Mpart,
    const float* __restrict__ Lpart, __bf16* __restrict__ Obf)
{
  const int bh = blockIdx.y;
  const int idx = blockIdx.x * 256 + threadIdx.x;   // 0..10239
  const int q = idx >> 5, d = idx & 31;
  if (q >= 300) return;
  const size_t rb = ((size_t)bh * 4) * 320 + q;
  float m0 = Mpart[rb], m1 = Mpart[rb + 320], m2 = Mpart[rb + 640], m3 = Mpart[rb + 960];
  float M = fmaxf(fmaxf(m0, m1), fmaxf(m2, m3));
  float w0 = Lpart[rb]       * __expf(m0 - M);
  float w1 = Lpart[rb + 320] * __expf(m1 - M);
  float w2 = Lpart[rb + 640] * __expf(m2 - M);
  float w3 = Lpart[rb + 960] * __expf(m3 - M);
  float S = w0 + w1 + w2 + w3;
  float o = w0 * (float)Opart[rb * 32 + d]
          + w1 * (float)Opart[(rb + 320) * 32 + d]
          + w2 * (float)Opart[(rb + 640) * 32 + d]
          + w3 * (float)Opart[(rb + 960) * 32 + d];
  int b = bh >> 3, h = bh & 7;
  Obf[((size_t)b * 300 + q) * 256 + h * 32 + d] = (__bf16)(o / S);
}

// ---------------------------------------------------------------------------
// Kernel D: out = identity + Obf @ W_o^T + b_o (unchanged).
__global__ __launch_bounds__(256) void out_proj_gemm(
    const __bf16* __restrict__ Obf, const float* __restrict__ W_o,
    const float* __restrict__ b_o, const float* __restrict__ query,
    float* __restrict__ out)
{
  __shared__ __bf16 Ws[256][72];
  const int tid  = threadIdx.x;
  const int wave = tid >> 6, lane = tid & 63;
  const int lrow = lane & 15, quad = lane >> 4;
  const int r0 = blockIdx.x * 64;

  f4 acc[16];
#pragma unroll
  for (int i = 0; i < 16; ++i) acc[i] = f4{0.f, 0.f, 0.f, 0.f};

  for (int kc0 = 0; kc0 < 256; kc0 += 64) {
#pragma unroll
    for (int it = 0; it < 16; ++it) {
      int idx = it * 256 + tid;
      int row = idx >> 4, c4 = idx & 15;
      float4 w = *(const float4*)(W_o + (size_t)row * 256 + kc0 + c4 * 4);
      __bf16* dp = &Ws[row][c4 * 4];
      dp[0] = (__bf16)w.x; dp[1] = (__bf16)w.y; dp[2] = (__bf16)w.z; dp[3] = (__bf16)w.w;
    }
    __syncthreads();
#pragma unroll
    for (int kk = 0; kk < 64; kk += 32) {
      b8v a = *(const b8v*)(Obf + (size_t)(r0 + wave * 16 + lrow) * 256 + kc0 + kk + quad * 8);
#pragma unroll
      for (int ct = 0; ct < 16; ++ct) {
        b8v bf = *(const b8v*)&Ws[ct * 16 + lrow][kk + quad * 8];
        acc[ct] = MFMA_BF16(a, bf, acc[ct]);
      }
    }
    __syncthreads();
  }
#pragma unroll
  for (int ct = 0; ct < 16; ++ct) {
    int col = ct * 16 + lrow;
    float bo = b_o[col];
#pragma unroll
    for (int r = 0; r < 4; ++r) {
      int row = r0 + wave * 16 + quad * 4 + r;
      int bb = row / 300, n = row % 300;
      size_t oaddr = ((size_t)n * 16 + bb) * 256 + col;
      out[oaddr] = acc[ct][r] + bo + query[oaddr];
    }
  }
}

// ---------------------------------------------------------------------------
extern "C" void kernel_launch(void* const* d_in, const int* in_sizes, int n_in,
                              void* d_out, int out_size, void* d_ws, size_t ws_size,
                              hipStream_t stream) {
  (void)in_sizes; (void)n_in; (void)out_size; (void)ws_size;
  const float* query      = (const float*)d_in[0];
  const float* key        = (const float*)d_in[1];
  const float* value      = (const float*)d_in[2];
  const float* query_pos  = (const float*)d_in[3];
  const float* key_pos    = (const float*)d_in[4];
  const float* query_sine = (const float*)d_in[5];
  const float* W_qc = (const float*)d_in[6];  const float* b_qc = (const float*)d_in[7];
  const float* W_qp = (const float*)d_in[8];  const float* b_qp = (const float*)d_in[9];
  const float* W_qs = (const float*)d_in[10]; const float* b_qs = (const float*)d_in[11];
  const float* W_kc = (const float*)d_in[12]; const float* b_kc = (const float*)d_in[13];
  const float* W_kp = (const float*)d_in[14]; const float* b_kp = (const float*)d_in[15];
  const float* W_v  = (const float*)d_in[16]; const float* b_v  = (const float*)d_in[17];
  const float* W_o  = (const float*)d_in[18]; const float* b_o  = (const float*)d_in[19];
  float* out = (float*)d_out;

  char* ws = (char*)d_ws;
  constexpr size_t WSL_BYTES = (size_t)8 * 96 * 256 * 2;     // 384 KiB
  constexpr size_t Q64_BYTES = (size_t)128 * 320 * 64 * 2;   //  5 MiB
  constexpr size_t OBF_BYTES = (size_t)16 * 300 * 256 * 2;   //  2.34 MiB
  constexpr size_t OPART_BYTES = (size_t)128 * 4 * 320 * 32 * 2;  // 10.49 MB
  constexpr size_t MPART_BYTES = (size_t)128 * 4 * 320 * 4;       // 0.655 MB
  __bf16* Wslice = (__bf16*)ws;
  __bf16* Q64 = (__bf16*)(ws + WSL_BYTES);
  __bf16* Obf = (__bf16*)(ws + WSL_BYTES + Q64_BYTES);
  char*  pbase = ws + WSL_BYTES + Q64_BYTES + OBF_BYTES;
  __bf16* Opart = (__bf16*)pbase;
  float*  Mpart = (float*)(pbase + OPART_BYTES);
  float*  Lpart = (float*)(pbase + OPART_BYTES + MPART_BYTES);

  hipLaunchKernelGGL(convert_w, dim3(192), dim3(256), 0, stream,
                     W_kc, W_kp, W_v, Wslice);
  hipLaunchKernelGGL(query_side_gemm, dim3(75), dim3(256), 0, stream,
                     query, query_pos, query_sine, W_qc, b_qc, W_qp, b_qp, W_qs, b_qs, Q64);
  hipLaunchKernelGGL(proj_attn, dim3(4, 128), dim3(256), 0, stream,
                     key, key_pos, value, Wslice, b_kc, b_kp, b_v, Q64,
                     Opart, Mpart, Lpart);
  hipLaunchKernelGGL(attn_combine, dim3(40, 128), dim3(256), 0, stream,
                     Opart, Mpart, Lpart, Obf);
  hipLaunchKernelGGL(out_proj_gemm, dim3(75), dim3(256), 0, stream,
                     Obf, W_o, b_o, query, out);
}

// Round 3
// 614.853 us; speedup vs baseline: 1.0656x; 1.0656x over previous
//
#include <hip/hip_runtime.h>
#include <cstdint>
#include <cstddef>

// MI355X / gfx950. bf16 MFMA implementation of ConditionalCrossAttention.
// score = (qc+qp)|(qc+qp+qs)  dot  kc|kp   (algebraic refold of the concat heads)
// R7: revert R6 fusion (8x X re-read, 367MB fetch). R5 structure restored.
//  - attn_part: L-split 4 -> 8, 3 blocks/CU (was barrier-bound at 2/CU, all
//    pipes <25%); combine handles 8 partials.
//  - convert_w folded into query-side kernel as extra blocks (launch order
//    query_conv -> key_side preserves the Wbf dependency); one fewer launch.
//  - key_side_gemm: verified R5 version, unchanged.

typedef float  f4  __attribute__((ext_vector_type(4)));
typedef __bf16 b8v __attribute__((ext_vector_type(8)));

#define MFMA_BF16(a, b, c) __builtin_amdgcn_mfma_f32_16x16x32_bf16((a), (b), (c), 0, 0, 0)

#define GLD_LDS16(gp, lp)                                             \
  __builtin_amdgcn_global_load_lds(                                   \
      (const __attribute__((address_space(1))) void*)(gp),            \
      (__attribute__((address_space(3))) void*)(lp), 16, 0, 0)

// K64 plane stride: 128 bh * 4096 l * 32 d
#define KPLANE ((size_t)128 * 4096 * 32)

// ---------------------------------------------------------------------------
// Kernel A: key-side linears. Block = (l-chunk of 128 tokens, batch), p = matrix.
// blockIdx.x: lc = x>>4 (0..31), batch = x&15. Output rows are consecutive l
// for fixed (batch,h) -> contiguous global stores. (Verified R5 version.)
__global__ __launch_bounds__(256, 2) void key_side_gemm(
    const float* __restrict__ key, const float* __restrict__ key_pos,
    const float* __restrict__ value, const __bf16* __restrict__ Wbf,
    const float* __restrict__ b_kc, const float* __restrict__ b_kp,
    const float* __restrict__ b_v,
    __bf16* __restrict__ K64, __bf16* __restrict__ V32)
{
  __shared__ char smem[65536];   // 2 x 32KB W dbuf; reused as 64KB output tile
  const int tid  = threadIdx.x;
  const int wave = tid >> 6, lane = tid & 63;
  const int lrow = lane & 15, quad = lane >> 4;
  const int p  = blockIdx.y;
  const int lc = blockIdx.x >> 4;          // l-chunk 0..31
  const int batch = blockIdx.x & 15;       // batch 0..15
  const int l0 = lc * 128;
  const int rowbase = (wave & 1) * 64;     // 2x2 wave grid: 64 rows x 128 cols each
  const int colbase = (wave >> 1) * 128;

  const float* __restrict__ X = (p == 0) ? key : (p == 1) ? key_pos : value;
  const __bf16* __restrict__ Wb = Wbf + (size_t)p * 65536;
  const float* __restrict__ bias = (p == 0) ? b_kc : (p == 1) ? b_kp : b_v;

  auto stageW = [&](int buf, int kc) {
#pragma unroll
    for (int it = 0; it < 8; ++it) {
      int slot = it * 256 + tid;            // 2048 granules of 16B
      int wr = slot >> 3, gp = slot & 7;
      int g  = gp ^ (wr & 7);
      GLD_LDS16(Wb + (size_t)wr * 256 + kc + g * 8, smem + buf * 32768 + slot * 16);
    }
  };
  auto readB = [&](int buf, int ct, int kk4) -> b8v {   // kk4 = kk/8 (0 or 4)
    int wr = colbase + ct * 16 + lrow;
    int g  = (kk4 + quad) ^ (wr & 7);
    return *(const b8v*)(smem + buf * 32768 + wr * 128 + g * 16);
  };
  // X row for token l, batch b lives at X[(l*16 + b)*256 + c]
  auto loadA = [&](float4* x0, float4* x1, int kc) {
#pragma unroll
    for (int rt = 0; rt < 4; ++rt) {
      const float* xp = X + ((size_t)(l0 + rowbase + rt * 16 + lrow) * 16 + batch) * 256
                          + kc + quad * 8;
      x0[rt] = *(const float4*)xp;
      x1[rt] = *(const float4*)(xp + 4);
    }
  };
  auto mk = [&](float4 x0, float4 x1) -> b8v {
    b8v t;
    t[0] = (__bf16)x0.x; t[1] = (__bf16)x0.y; t[2] = (__bf16)x0.z; t[3] = (__bf16)x0.w;
    t[4] = (__bf16)x1.x; t[5] = (__bf16)x1.y; t[6] = (__bf16)x1.z; t[7] = (__bf16)x1.w;
    return t;
  };

  f4 acc[4][8];
#pragma unroll
  for (int i = 0; i < 4; ++i)
#pragma unroll
    for (int j = 0; j < 8; ++j) acc[i][j] = f4{0.f, 0.f, 0.f, 0.f};

  float4 c0[4], c1[4], d0[4], d1[4];
  loadA(c0, c1, 0);
  stageW(0, 0);
  __syncthreads();

  for (int s = 0; s < 4; ++s) {
    const int kc0 = s * 64, buf = s & 1;
    loadA(d0, d1, kc0 + 32);
    if (s < 3) stageW(buf ^ 1, kc0 + 64);

    b8v a[4];
#pragma unroll
    for (int rt = 0; rt < 4; ++rt) a[rt] = mk(c0[rt], c1[rt]);
#pragma unroll
    for (int ct = 0; ct < 8; ++ct) {
      b8v bfr = readB(buf, ct, 0);
#pragma unroll
      for (int rt = 0; rt < 4; ++rt) acc[rt][ct] = MFMA_BF16(a[rt], bfr, acc[rt][ct]);
    }

    if (s < 3) loadA(c0, c1, kc0 + 64);

#pragma unroll
    for (int rt = 0; rt < 4; ++rt) a[rt] = mk(d0[rt], d1[rt]);
#pragma unroll
    for (int ct = 0; ct < 8; ++ct) {
      b8v bfr = readB(buf, ct, 4);
#pragma unroll
      for (int rt = 0; rt < 4; ++rt) acc[rt][ct] = MFMA_BF16(a[rt], bfr, acc[rt][ct]);
    }
    __syncthreads();
  }

  // epilogue: acc -> swizzled LDS tile [128][256] bf16 -> contiguous stores.
  __bf16* Os = (__bf16*)smem;
#pragma unroll
  for (int ct = 0; ct < 8; ++ct) {
    int col = colbase + ct * 16 + lrow;
    float bv = bias[col];
    int cg = col >> 3, cr = col & 7;
#pragma unroll
    for (int rt = 0; rt < 4; ++rt)
#pragma unroll
      for (int r = 0; r < 4; ++r) {
        int row = rowbase + rt * 16 + quad * 4 + r;
        int g = cg ^ ((row ^ (row >> 3)) & 7);
        Os[row * 256 + g * 8 + cr] = (__bf16)(acc[rt][ct][r] + bv);
      }
  }
  __syncthreads();
  // stores: per h, 128 consecutive rows of 32 bf16 (64 B) -> contiguous 8 KB runs
#pragma unroll
  for (int it = 0; it < 16; ++it) {
    int h   = it >> 1;
    int row = (it & 1) * 64 + (tid >> 2);
    int seg = tid & 3;
    int g = (h * 4 + seg) ^ ((row ^ (row >> 3)) & 7);
    uint4 v = *(const uint4*)(Os + row * 256 + g * 8);
    size_t rowidx = ((size_t)(batch * 8 + h) * 4096) + l0 + row;
    if (p == 2) *(uint4*)(V32 + rowidx * 32 + seg * 8) = v;
    else        *(uint4*)(K64 + (size_t)p * KPLANE + rowidx * 32 + seg * 8) = v;
  }
}

// ---------------------------------------------------------------------------
// Kernel B: query-side projections + (blocks >= 75) the W_k*/W_v fp32->bf16
// conversion. Both partitions are independent; this kernel runs before
// key_side_gemm so the Wbf dependency is satisfied by stream order.
__global__ __launch_bounds__(256) void query_conv(
    const float* __restrict__ query, const float* __restrict__ query_pos,
    const float* __restrict__ query_sine,
    const float* __restrict__ W_qc, const float* __restrict__ b_qc,
    const float* __restrict__ W_qp, const float* __restrict__ b_qp,
    const float* __restrict__ W_qs, const float* __restrict__ b_qs,
    __bf16* __restrict__ Q64,
    const float* __restrict__ W_kc, const float* __restrict__ W_kp,
    const float* __restrict__ W_v, __bf16* __restrict__ Wbf)
{
  __shared__ __bf16 Ws[256][72];
  if (blockIdx.x >= 75) {
    // convert partition: 192 blocks
    int i = (blockIdx.x - 75) * 256 + threadIdx.x;   // 0 .. 49151
    int base = i * 4;
    int m = base >> 16;
    int off = base & 65535;
    const float* W = (m == 0) ? W_kc : (m == 1) ? W_kp : W_v;
    float4 v = *(const float4*)(W + off);
    __bf16 o[4];
    o[0] = (__bf16)v.x; o[1] = (__bf16)v.y; o[2] = (__bf16)v.z; o[3] = (__bf16)v.w;
    *(uint2*)(Wbf + (size_t)m * 65536 + off) = *(uint2*)o;
    return;
  }
  const int tid  = threadIdx.x;
  const int wave = tid >> 6, lane = tid & 63;
  const int lrow = lane & 15, quad = lane >> 4;
  const int r0 = blockIdx.x * 64;

  f4 acc[16];
#pragma unroll
  for (int i = 0; i < 16; ++i) acc[i] = f4{0.f, 0.f, 0.f, 0.f};

  for (int kc = 0; kc < 768; kc += 64) {
    const float* X; const float* W;
    if (kc < 256)      { X = query;      W = W_qc; }
    else if (kc < 512) { X = query_pos;  W = W_qp; }
    else               { X = query_sine; W = W_qs; }
    const int ko = kc & 255;
#pragma unroll
    for (int it = 0; it < 16; ++it) {
      int idx = it * 256 + tid;
      int row = idx >> 4, c4 = idx & 15;
      float4 w = *(const float4*)(W + (size_t)row * 256 + ko + c4 * 4);
      __bf16* dp = &Ws[row][c4 * 4];
      dp[0] = (__bf16)w.x; dp[1] = (__bf16)w.y; dp[2] = (__bf16)w.z; dp[3] = (__bf16)w.w;
    }
    __syncthreads();
#pragma unroll
    for (int kk = 0; kk < 64; kk += 32) {
      const float* xp = X + (size_t)(r0 + wave * 16 + lrow) * 256 + ko + kk + quad * 8;
      float4 x0 = *(const float4*)xp;
      float4 x1 = *(const float4*)(xp + 4);
      b8v a;
      a[0] = (__bf16)x0.x; a[1] = (__bf16)x0.y; a[2] = (__bf16)x0.z; a[3] = (__bf16)x0.w;
      a[4] = (__bf16)x1.x; a[5] = (__bf16)x1.y; a[6] = (__bf16)x1.z; a[7] = (__bf16)x1.w;
#pragma unroll
      for (int ct = 0; ct < 16; ++ct) {
        b8v bf = *(const b8v*)&Ws[ct * 16 + lrow][kk + quad * 8];
        acc[ct] = MFMA_BF16(a, bf, acc[ct]);
      }
    }
    __syncthreads();
    if (kc == 448) {
#pragma unroll
      for (int ct = 0; ct < 16; ++ct) {
        int col = ct * 16 + lrow;
        float bsum = b_qc[col] + b_qp[col];
        int h = col >> 5, d = col & 31;
#pragma unroll
        for (int r = 0; r < 4; ++r) {
          int row = r0 + wave * 16 + quad * 4 + r;
          int n = row >> 4, bb = row & 15;
          Q64[((size_t)(bb * 8 + h) * 320 + n) * 64 + d] = (__bf16)((acc[ct][r] + bsum) * 0.125f);
        }
      }
    }
  }
#pragma unroll
  for (int ct = 0; ct < 16; ++ct) {
    int col = ct * 16 + lrow;
    float bsum = b_qc[col] + b_qp[col] + b_qs[col];
    int h = col >> 5, d = col & 31;
#pragma unroll
    for (int r = 0; r < 4; ++r) {
      int row = r0 + wave * 16 + quad * 4 + r;
      int n = row >> 4, bb = row & 15;
      Q64[((size_t)(bb * 8 + h) * 320 + n) * 64 + 32 + d] = (__bf16)((acc[ct][r] + bsum) * 0.125f);
    }
  }
}

// ---------------------------------------------------------------------------
// Kernel C v7: flash attention, 8-way L-split, S^T orientation, 3 blocks/CU.
// Grid (8 ls, 128 bh), 256 threads. Each block: 4 chunks of 128 tokens.
__global__ __launch_bounds__(256, 3) void attn_part(
    const __bf16* __restrict__ Q64, const __bf16* __restrict__ K64,
    const __bf16* __restrict__ V32,
    __bf16* __restrict__ Opart, float* __restrict__ Mpart, float* __restrict__ Lpart)
{
  __shared__ __bf16 Ks[128 * 64];     // 16 KB, xor-swizzled 16B granules
  __shared__ __bf16 Vt[32][136];      // 8.5 KB, natural [d][l]
  __shared__ __bf16 Pt[4][16][136];   // 17.4 KB, per-wave P^T [q][l]
  const int tid  = threadIdx.x;
  const int wave = tid >> 6, lane = tid & 63;
  const int lrow = lane & 15, quad = lane >> 4;
  const int ls = blockIdx.x, bh = blockIdx.y;
  const int l0base = ls * 512;

  const __bf16* Kb0 = K64 + (size_t)bh * 4096 * 32;        // kc plane
  const __bf16* Kb1 = Kb0 + KPLANE;                         // kp plane
  const __bf16* Vb  = V32 + (size_t)bh * 4096 * 32;

  // Q fragments: 5 tiles of 16 q-rows per wave; serves as MFMA B operand.
  b8v qa0[5], qa1[5];
#pragma unroll
  for (int t = 0; t < 5; ++t) {
    const __bf16* Qb = Q64 + ((size_t)bh * 320 + wave * 80 + t * 16 + lrow) * 64;
    qa0[t] = *(const b8v*)(Qb + quad * 8);
    qa1[t] = *(const b8v*)(Qb + 32 + quad * 8);
  }

  // V staging map: thread (vs = d-octet, vrh = l-pair) loads rows 2vrh, 2vrh+1
  const int vs = tid & 3, vrh = tid >> 2;    // vrh 0..63

  auto loadKV = [&](uint4* kr, uint4* vv, int c) {
    int l0 = l0base + c * 128;
#pragma unroll
    for (int it = 0; it < 4; ++it) {
      int slot = it * 256 + tid, row = slot >> 3, gs = slot & 7;
      int g = gs ^ (row & 7);
      const __bf16* src = (g < 4)
          ? (Kb0 + (size_t)(l0 + row) * 32 + g * 8)
          : (Kb1 + (size_t)(l0 + row) * 32 + (g - 4) * 8);
      kr[it] = *(const uint4*)src;
    }
    vv[0] = *(const uint4*)(Vb + (size_t)(l0 + 2 * vrh) * 32 + vs * 8);
    vv[1] = *(const uint4*)(Vb + (size_t)(l0 + 2 * vrh + 1) * 32 + vs * 8);
  };
  auto stage = [&](const uint4* kr, const uint4* vv) {
#pragma unroll
    for (int it = 0; it < 4; ++it) {
      int slot = it * 256 + tid;
      *(uint4*)((char*)Ks + slot * 16) = kr[it];
    }
    __bf16 a[8], b[8];
    *(uint4*)a = vv[0]; *(uint4*)b = vv[1];
#pragma unroll
    for (int j = 0; j < 8; ++j) {
      __bf16 pr[2] = {a[j], b[j]};
      *(uint32_t*)&Vt[vs * 8 + j][2 * vrh] = *(const uint32_t*)pr;
    }
  };
  auto readKA = [&](int wr, int g) -> b8v {   // K[l=wr][c = g*8 .. +8]
    int gs = g ^ (wr & 7);
    return *(const b8v*)((const char*)Ks + wr * 128 + gs * 16);
  };

  float mst[5], lst[5];
  f4 oacc[5][2];
#pragma unroll
  for (int t = 0; t < 5; ++t) {
    mst[t] = -1e30f; lst[t] = 0.f;
    oacc[t][0] = f4{0.f, 0.f, 0.f, 0.f};
    oacc[t][1] = f4{0.f, 0.f, 0.f, 0.f};
  }

  auto compute = [&]() {
#pragma unroll
    for (int t = 0; t < 5; ++t) {
      // S^T tiles: row l = ct*16 + quad*4 + r, col q = lrow
      f4 sc[8];
#pragma unroll
      for (int ct = 0; ct < 8; ++ct) {
        b8v ka0 = readKA(ct * 16 + lrow, quad);
        b8v ka1 = readKA(ct * 16 + lrow, 4 + quad);
        f4 z = f4{0.f, 0.f, 0.f, 0.f};
        z = MFMA_BF16(ka0, qa0[t], z);
        z = MFMA_BF16(ka1, qa1[t], z);
        sc[ct] = z;
      }
      // softmax over l: in-lane (32 vals) + cross-quad (lane^16, lane^32)
      float mx = sc[0][0];
#pragma unroll
      for (int ct = 0; ct < 8; ++ct)
#pragma unroll
        for (int r = 0; r < 4; ++r) mx = fmaxf(mx, sc[ct][r]);
      mx = fmaxf(mx, __shfl_xor(mx, 16));
      mx = fmaxf(mx, __shfl_xor(mx, 32));
      float mnew = fmaxf(mst[t], mx);
      float alpha = __expf(mst[t] - mnew);
      mst[t] = mnew;
      float rsum = 0.f;
#pragma unroll
      for (int ct = 0; ct < 8; ++ct)
#pragma unroll
        for (int r = 0; r < 4; ++r) {
          sc[ct][r] = __expf(sc[ct][r] - mnew);
          rsum += sc[ct][r];
        }
      rsum += __shfl_xor(rsum, 16);
      rsum += __shfl_xor(rsum, 32);
      lst[t] = lst[t] * alpha + rsum;
#pragma unroll
      for (int c2 = 0; c2 < 2; ++c2)
#pragma unroll
        for (int r = 0; r < 4; ++r) oacc[t][c2][r] *= alpha;

      // P^T -> per-wave LDS [q=lrow][l]; b64 writes (4 consecutive l per reg)
#pragma unroll
      for (int ct = 0; ct < 8; ++ct) {
        __bf16 p4[4];
#pragma unroll
        for (int r = 0; r < 4; ++r) p4[r] = (__bf16)sc[ct][r];
        *(uint2*)&Pt[wave][lrow][ct * 16 + quad * 4] = *(const uint2*)p4;
      }
      // O^T += V^T P^T
#pragma unroll
      for (int kt = 0; kt < 4; ++kt) {
        b8v pb = *(const b8v*)&Pt[wave][lrow][kt * 32 + quad * 8];
#pragma unroll
        for (int c2 = 0; c2 < 2; ++c2) {
          b8v va = *(const b8v*)&Vt[c2 * 16 + lrow][kt * 32 + quad * 8];
          oacc[t][c2] = MFMA_BF16(va, pb, oacc[t][c2]);
        }
      }
    }
  };

  uint4 kA[4], vA[2], kB[4], vB[2];
  loadKV(kA, vA, 0);
  for (int c = 0; c < 4; c += 2) {
    __syncthreads();
    stage(kA, vA);
    loadKV(kB, vB, c + 1);           // prefetch, in flight across compute
    __syncthreads();
    compute();
    __syncthreads();
    stage(kB, vB);
    if (c + 2 < 4) loadKV(kA, vA, c + 2);
    __syncthreads();
    compute();
  }

  // epilogue: O^T[d][q] -> Opart[q][d] (b64 packed), m/l per q
  const size_t pbase = ((size_t)bh * 8 + ls) * 320;
#pragma unroll
  for (int t = 0; t < 5; ++t) {
    int q = wave * 80 + t * 16 + lrow;
    float inv = 1.0f / lst[t];
#pragma unroll
    for (int c2 = 0; c2 < 2; ++c2) {
      __bf16 o4[4];
#pragma unroll
      for (int r = 0; r < 4; ++r) o4[r] = (__bf16)(oacc[t][c2][r] * inv);
      *(uint2*)&Opart[(pbase + q) * 32 + c2 * 16 + quad * 4] = *(const uint2*)o4;
    }
    if (quad == 0) {
      Mpart[pbase + q] = mst[t];
      Lpart[pbase + q] = lst[t];
    }
  }
}

// ---------------------------------------------------------------------------
// Kernel C2: combine 8 L-split partials -> Obf[b][n][256].
__global__ __launch_bounds__(256) void attn_combine(
    const __bf16* __restrict__ Opart, const float* __restrict__ Mpart,
    const float* __restrict__ Lpart, __bf16* __restrict__ Obf)
{
  const int bh = blockIdx.y;
  const int idx = blockIdx.x * 256 + threadIdx.x;   // 0..10239
  const int q = idx >> 5, d = idx & 31;
  if (q >= 300) return;
  const size_t rb = (size_t)bh * 8 * 320 + q;
  float m[8];
#pragma unroll
  for (int j = 0; j < 8; ++j) m[j] = Mpart[rb + j * 320];
  float M = m[0];
#pragma unroll
  for (int j = 1; j < 8; ++j) M = fmaxf(M, m[j]);
  float S = 0.f, o = 0.f;
#pragma unroll
  for (int j = 0; j < 8; ++j) {
    float w = Lpart[rb + j * 320] * __expf(m[j] - M);
    S += w;
    o += w * (float)Opart[(rb + j * 320) * 32 + d];
  }
  int b = bh >> 3, h = bh & 7;
  Obf[((size_t)b * 300 + q) * 256 + h * 32 + d] = (__bf16)(o / S);
}

// ---------------------------------------------------------------------------
// Kernel D: out = identity + Obf @ W_o^T + b_o (unchanged).
__global__ __launch_bounds__(256) void out_proj_gemm(
    const __bf16* __restrict__ Obf, const float* __restrict__ W_o,
    const float* __restrict__ b_o, const float* __restrict__ query,
    float* __restrict__ out)
{
  __shared__ __bf16 Ws[256][72];
  const int tid  = threadIdx.x;
  const int wave = tid >> 6, lane = tid & 63;
  const int lrow = lane & 15, quad = lane >> 4;
  const int r0 = blockIdx.x * 64;

  f4 acc[16];
#pragma unroll
  for (int i = 0; i < 16; ++i) acc[i] = f4{0.f, 0.f, 0.f, 0.f};

  for (int kc0 = 0; kc0 < 256; kc0 += 64) {
#pragma unroll
    for (int it = 0; it < 16; ++it) {
      int idx = it * 256 + tid;
      int row = idx >> 4, c4 = idx & 15;
      float4 w = *(const float4*)(W_o + (size_t)row * 256 + kc0 + c4 * 4);
      __bf16* dp = &Ws[row][c4 * 4];
      dp[0] = (__bf16)w.x; dp[1] = (__bf16)w.y; dp[2] = (__bf16)w.z; dp[3] = (__bf16)w.w;
    }
    __syncthreads();
#pragma unroll
    for (int kk = 0; kk < 64; kk += 32) {
      b8v a = *(const b8v*)(Obf + (size_t)(r0 + wave * 16 + lrow) * 256 + kc0 + kk + quad * 8);
#pragma unroll
      for (int ct = 0; ct < 16; ++ct) {
        b8v bf = *(const b8v*)&Ws[ct * 16 + lrow][kk + quad * 8];
        acc[ct] = MFMA_BF16(a, bf, acc[ct]);
      }
    }
    __syncthreads();
  }
#pragma unroll
  for (int ct = 0; ct < 16; ++ct) {
    int col = ct * 16 + lrow;
    float bo = b_o[col];
#pragma unroll
    for (int r = 0; r < 4; ++r) {
      int row = r0 + wave * 16 + quad * 4 + r;
      int bb = row / 300, n = row % 300;
      size_t oaddr = ((size_t)n * 16 + bb) * 256 + col;
      out[oaddr] = acc[ct][r] + bo + query[oaddr];
    }
  }
}

// ---------------------------------------------------------------------------
extern "C" void kernel_launch(void* const* d_in, const int* in_sizes, int n_in,
                              void* d_out, int out_size, void* d_ws, size_t ws_size,
                              hipStream_t stream) {
  (void)in_sizes; (void)n_in; (void)out_size; (void)ws_size;
  const float* query      = (const float*)d_in[0];
  const float* key        = (const float*)d_in[1];
  const float* value      = (const float*)d_in[2];
  const float* query_pos  = (const float*)d_in[3];
  const float* key_pos    = (const float*)d_in[4];
  const float* query_sine = (const float*)d_in[5];
  const float* W_qc = (const float*)d_in[6];  const float* b_qc = (const float*)d_in[7];
  const float* W_qp = (const float*)d_in[8];  const float* b_qp = (const float*)d_in[9];
  const float* W_qs = (const float*)d_in[10]; const float* b_qs = (const float*)d_in[11];
  const float* W_kc = (const float*)d_in[12]; const float* b_kc = (const float*)d_in[13];
  const float* W_kp = (const float*)d_in[14]; const float* b_kp = (const float*)d_in[15];
  const float* W_v  = (const float*)d_in[16]; const float* b_v  = (const float*)d_in[17];
  const float* W_o  = (const float*)d_in[18]; const float* b_o  = (const float*)d_in[19];
  float* out = (float*)d_out;

  char* ws = (char*)d_ws;
  constexpr size_t K64_BYTES = (size_t)128 * 4096 * 64 * 2;  // 64 MiB (2 planes of 32)
  constexpr size_t V32_BYTES = (size_t)128 * 4096 * 32 * 2;  // 32 MiB
  constexpr size_t Q64_BYTES = (size_t)128 * 320 * 64 * 2;   //  5 MiB
  constexpr size_t OBF_BYTES = (size_t)16 * 300 * 256 * 2;   //  2.34 MiB
  constexpr size_t WBF_BYTES = (size_t)3 * 256 * 256 * 2;    //  0.375 MiB
  constexpr size_t OPART_BYTES = (size_t)128 * 8 * 320 * 32 * 2;  // 20 MiB
  constexpr size_t MPART_BYTES = (size_t)128 * 8 * 320 * 4;       // 1.25 MiB
  __bf16* K64 = (__bf16*)ws;
  __bf16* V32 = (__bf16*)(ws + K64_BYTES);
  __bf16* Q64 = (__bf16*)(ws + K64_BYTES + V32_BYTES);
  __bf16* Obf = (__bf16*)(ws + K64_BYTES + V32_BYTES + Q64_BYTES);
  __bf16* Wbf = (__bf16*)(ws + K64_BYTES + V32_BYTES + Q64_BYTES + OBF_BYTES);
  char*  pbase = ws + K64_BYTES + V32_BYTES + Q64_BYTES + OBF_BYTES + WBF_BYTES;
  __bf16* Opart = (__bf16*)pbase;
  float*  Mpart = (float*)(pbase + OPART_BYTES);
  float*  Lpart = (float*)(pbase + OPART_BYTES + MPART_BYTES);

  hipLaunchKernelGGL(query_conv, dim3(267), dim3(256), 0, stream,
                     query, query_pos, query_sine, W_qc, b_qc, W_qp, b_qp, W_qs, b_qs, Q64,
                     W_kc, W_kp, W_v, Wbf);
  hipLaunchKernelGGL(key_side_gemm, dim3(512, 3), dim3(256), 0, stream,
                     key, key_pos, value, Wbf, b_kc, b_kp, b_v, K64, V32);
  hipLaunchKernelGGL(attn_part, dim3(8, 128), dim3(256), 0, stream,
                     Q64, K64, V32, Opart, Mpart, Lpart);
  hipLaunchKernelGGL(attn_combine, dim3(40, 128), dim3(256), 0, stream,
                     Opart, Mpart, Lpart, Obf);
  hipLaunchKernelGGL(out_proj_gemm, dim3(75), dim3(256), 0, stream,
                     Obf, W_o, b_o, query, out);
}

// Round 5
// 456.715 us; speedup vs baseline: 1.4346x; 1.3463x over previous
//
#include <hip/hip_runtime.h>
#include <cstdint>
#include <cstddef>

// MI355X / gfx950. bf16 MFMA implementation of ConditionalCrossAttention.
// score = (qc+qp)|(qc+qp+qs)  dot  kc|kp   (algebraic refold of the concat heads)
// R8 (resubmit; previous round failed in infra, not kernel): R7's 8-way
// L-split kept, but __launch_bounds__(256,2) restored (R7's (256,3) drove the
// allocator to 84 VGPR -> ~470MB scratch spill traffic, attn 130->285us).
// With 128 VGPR + 42.5KB LDS, HW occupancy = 3 blocks/CU on its own; grid
// 1024 gives 4 blocks/CU of work.

typedef float  f4  __attribute__((ext_vector_type(4)));
typedef __bf16 b8v __attribute__((ext_vector_type(8)));

#define MFMA_BF16(a, b, c) __builtin_amdgcn_mfma_f32_16x16x32_bf16((a), (b), (c), 0, 0, 0)

#define GLD_LDS16(gp, lp)                                             \
  __builtin_amdgcn_global_load_lds(                                   \
      (const __attribute__((address_space(1))) void*)(gp),            \
      (__attribute__((address_space(3))) void*)(lp), 16, 0, 0)

// K64 plane stride: 128 bh * 4096 l * 32 d
#define KPLANE ((size_t)128 * 4096 * 32)

// ---------------------------------------------------------------------------
// Kernel A: key-side linears. Block = (l-chunk of 128 tokens, batch), p = matrix.
// blockIdx.x: lc = x>>4 (0..31), batch = x&15. Output rows are consecutive l
// for fixed (batch,h) -> contiguous global stores. (Verified R5 version.)
__global__ __launch_bounds__(256, 2) void key_side_gemm(
    const float* __restrict__ key, const float* __restrict__ key_pos,
    const float* __restrict__ value, const __bf16* __restrict__ Wbf,
    const float* __restrict__ b_kc, const float* __restrict__ b_kp,
    const float* __restrict__ b_v,
    __bf16* __restrict__ K64, __bf16* __restrict__ V32)
{
  __shared__ char smem[65536];   // 2 x 32KB W dbuf; reused as 64KB output tile
  const int tid  = threadIdx.x;
  const int wave = tid >> 6, lane = tid & 63;
  const int lrow = lane & 15, quad = lane >> 4;
  const int p  = blockIdx.y;
  const int lc = blockIdx.x >> 4;          // l-chunk 0..31
  const int batch = blockIdx.x & 15;       // batch 0..15
  const int l0 = lc * 128;
  const int rowbase = (wave & 1) * 64;     // 2x2 wave grid: 64 rows x 128 cols each
  const int colbase = (wave >> 1) * 128;

  const float* __restrict__ X = (p == 0) ? key : (p == 1) ? key_pos : value;
  const __bf16* __restrict__ Wb = Wbf + (size_t)p * 65536;
  const float* __restrict__ bias = (p == 0) ? b_kc : (p == 1) ? b_kp : b_v;

  auto stageW = [&](int buf, int kc) {
#pragma unroll
    for (int it = 0; it < 8; ++it) {
      int slot = it * 256 + tid;            // 2048 granules of 16B
      int wr = slot >> 3, gp = slot & 7;
      int g  = gp ^ (wr & 7);
      GLD_LDS16(Wb + (size_t)wr * 256 + kc + g * 8, smem + buf * 32768 + slot * 16);
    }
  };
  auto readB = [&](int buf, int ct, int kk4) -> b8v {   // kk4 = kk/8 (0 or 4)
    int wr = colbase + ct * 16 + lrow;
    int g  = (kk4 + quad) ^ (wr & 7);
    return *(const b8v*)(smem + buf * 32768 + wr * 128 + g * 16);
  };
  // X row for token l, batch b lives at X[(l*16 + b)*256 + c]
  auto loadA = [&](float4* x0, float4* x1, int kc) {
#pragma unroll
    for (int rt = 0; rt < 4; ++rt) {
      const float* xp = X + ((size_t)(l0 + rowbase + rt * 16 + lrow) * 16 + batch) * 256
                          + kc + quad * 8;
      x0[rt] = *(const float4*)xp;
      x1[rt] = *(const float4*)(xp + 4);
    }
  };
  auto mk = [&](float4 x0, float4 x1) -> b8v {
    b8v t;
    t[0] = (__bf16)x0.x; t[1] = (__bf16)x0.y; t[2] = (__bf16)x0.z; t[3] = (__bf16)x0.w;
    t[4] = (__bf16)x1.x; t[5] = (__bf16)x1.y; t[6] = (__bf16)x1.z; t[7] = (__bf16)x1.w;
    return t;
  };

  f4 acc[4][8];
#pragma unroll
  for (int i = 0; i < 4; ++i)
#pragma unroll
    for (int j = 0; j < 8; ++j) acc[i][j] = f4{0.f, 0.f, 0.f, 0.f};

  float4 c0[4], c1[4], d0[4], d1[4];
  loadA(c0, c1, 0);
  stageW(0, 0);
  __syncthreads();

  for (int s = 0; s < 4; ++s) {
    const int kc0 = s * 64, buf = s & 1;
    loadA(d0, d1, kc0 + 32);
    if (s < 3) stageW(buf ^ 1, kc0 + 64);

    b8v a[4];
#pragma unroll
    for (int rt = 0; rt < 4; ++rt) a[rt] = mk(c0[rt], c1[rt]);
#pragma unroll
    for (int ct = 0; ct < 8; ++ct) {
      b8v bfr = readB(buf, ct, 0);
#pragma unroll
      for (int rt = 0; rt < 4; ++rt) acc[rt][ct] = MFMA_BF16(a[rt], bfr, acc[rt][ct]);
    }

    if (s < 3) loadA(c0, c1, kc0 + 64);

#pragma unroll
    for (int rt = 0; rt < 4; ++rt) a[rt] = mk(d0[rt], d1[rt]);
#pragma unroll
    for (int ct = 0; ct < 8; ++ct) {
      b8v bfr = readB(buf, ct, 4);
#pragma unroll
      for (int rt = 0; rt < 4; ++rt) acc[rt][ct] = MFMA_BF16(a[rt], bfr, acc[rt][ct]);
    }
    __syncthreads();
  }

  // epilogue: acc -> swizzled LDS tile [128][256] bf16 -> contiguous stores.
  __bf16* Os = (__bf16*)smem;
#pragma unroll
  for (int ct = 0; ct < 8; ++ct) {
    int col = colbase + ct * 16 + lrow;
    float bv = bias[col];
    int cg = col >> 3, cr = col & 7;
#pragma unroll
    for (int rt = 0; rt < 4; ++rt)
#pragma unroll
      for (int r = 0; r < 4; ++r) {
        int row = rowbase + rt * 16 + quad * 4 + r;
        int g = cg ^ ((row ^ (row >> 3)) & 7);
        Os[row * 256 + g * 8 + cr] = (__bf16)(acc[rt][ct][r] + bv);
      }
  }
  __syncthreads();
  // stores: per h, 128 consecutive rows of 32 bf16 (64 B) -> contiguous 8 KB runs
#pragma unroll
  for (int it = 0; it < 16; ++it) {
    int h   = it >> 1;
    int row = (it & 1) * 64 + (tid >> 2);
    int seg = tid & 3;
    int g = (h * 4 + seg) ^ ((row ^ (row >> 3)) & 7);
    uint4 v = *(const uint4*)(Os + row * 256 + g * 8);
    size_t rowidx = ((size_t)(batch * 8 + h) * 4096) + l0 + row;
    if (p == 2) *(uint4*)(V32 + rowidx * 32 + seg * 8) = v;
    else        *(uint4*)(K64 + (size_t)p * KPLANE + rowidx * 32 + seg * 8) = v;
  }
}

// ---------------------------------------------------------------------------
// Kernel B: query-side projections + (blocks >= 75) the W_k*/W_v fp32->bf16
// conversion. Both partitions are independent; this kernel runs before
// key_side_gemm so the Wbf dependency is satisfied by stream order.
__global__ __launch_bounds__(256) void query_conv(
    const float* __restrict__ query, const float* __restrict__ query_pos,
    const float* __restrict__ query_sine,
    const float* __restrict__ W_qc, const float* __restrict__ b_qc,
    const float* __restrict__ W_qp, const float* __restrict__ b_qp,
    const float* __restrict__ W_qs, const float* __restrict__ b_qs,
    __bf16* __restrict__ Q64,
    const float* __restrict__ W_kc, const float* __restrict__ W_kp,
    const float* __restrict__ W_v, __bf16* __restrict__ Wbf)
{
  __shared__ __bf16 Ws[256][72];
  if (blockIdx.x >= 75) {
    // convert partition: 192 blocks
    int i = (blockIdx.x - 75) * 256 + threadIdx.x;   // 0 .. 49151
    int base = i * 4;
    int m = base >> 16;
    int off = base & 65535;
    const float* W = (m == 0) ? W_kc : (m == 1) ? W_kp : W_v;
    float4 v = *(const float4*)(W + off);
    __bf16 o[4];
    o[0] = (__bf16)v.x; o[1] = (__bf16)v.y; o[2] = (__bf16)v.z; o[3] = (__bf16)v.w;
    *(uint2*)(Wbf + (size_t)m * 65536 + off) = *(uint2*)o;
    return;
  }
  const int tid  = threadIdx.x;
  const int wave = tid >> 6, lane = tid & 63;
  const int lrow = lane & 15, quad = lane >> 4;
  const int r0 = blockIdx.x * 64;

  f4 acc[16];
#pragma unroll
  for (int i = 0; i < 16; ++i) acc[i] = f4{0.f, 0.f, 0.f, 0.f};

  for (int kc = 0; kc < 768; kc += 64) {
    const float* X; const float* W;
    if (kc < 256)      { X = query;      W = W_qc; }
    else if (kc < 512) { X = query_pos;  W = W_qp; }
    else               { X = query_sine; W = W_qs; }
    const int ko = kc & 255;
#pragma unroll
    for (int it = 0; it < 16; ++it) {
      int idx = it * 256 + tid;
      int row = idx >> 4, c4 = idx & 15;
      float4 w = *(const float4*)(W + (size_t)row * 256 + ko + c4 * 4);
      __bf16* dp = &Ws[row][c4 * 4];
      dp[0] = (__bf16)w.x; dp[1] = (__bf16)w.y; dp[2] = (__bf16)w.z; dp[3] = (__bf16)w.w;
    }
    __syncthreads();
#pragma unroll
    for (int kk = 0; kk < 64; kk += 32) {
      const float* xp = X + (size_t)(r0 + wave * 16 + lrow) * 256 + ko + kk + quad * 8;
      float4 x0 = *(const float4*)xp;
      float4 x1 = *(const float4*)(xp + 4);
      b8v a;
      a[0] = (__bf16)x0.x; a[1] = (__bf16)x0.y; a[2] = (__bf16)x0.z; a[3] = (__bf16)x0.w;
      a[4] = (__bf16)x1.x; a[5] = (__bf16)x1.y; a[6] = (__bf16)x1.z; a[7] = (__bf16)x1.w;
#pragma unroll
      for (int ct = 0; ct < 16; ++ct) {
        b8v bf = *(const b8v*)&Ws[ct * 16 + lrow][kk + quad * 8];
        acc[ct] = MFMA_BF16(a, bf, acc[ct]);
      }
    }
    __syncthreads();
    if (kc == 448) {
#pragma unroll
      for (int ct = 0; ct < 16; ++ct) {
        int col = ct * 16 + lrow;
        float bsum = b_qc[col] + b_qp[col];
        int h = col >> 5, d = col & 31;
#pragma unroll
        for (int r = 0; r < 4; ++r) {
          int row = r0 + wave * 16 + quad * 4 + r;
          int n = row >> 4, bb = row & 15;
          Q64[((size_t)(bb * 8 + h) * 320 + n) * 64 + d] = (__bf16)((acc[ct][r] + bsum) * 0.125f);
        }
      }
    }
  }
#pragma unroll
  for (int ct = 0; ct < 16; ++ct) {
    int col = ct * 16 + lrow;
    float bsum = b_qc[col] + b_qp[col] + b_qs[col];
    int h = col >> 5, d = col & 31;
#pragma unroll
    for (int r = 0; r < 4; ++r) {
      int row = r0 + wave * 16 + quad * 4 + r;
      int n = row >> 4, bb = row & 15;
      Q64[((size_t)(bb * 8 + h) * 320 + n) * 64 + 32 + d] = (__bf16)((acc[ct][r] + bsum) * 0.125f);
    }
  }
}

// ---------------------------------------------------------------------------
// Kernel C v8: flash attention, 8-way L-split, S^T orientation.
// Grid (8 ls, 128 bh), 256 threads, launch_bounds (256,2) -> 128 VGPR, no
// spills; HW occupancy 3 blocks/CU (LDS-limited). 4 chunks of 128 tokens.
__global__ __launch_bounds__(256, 2) void attn_part(
    const __bf16* __restrict__ Q64, const __bf16* __restrict__ K64,
    const __bf16* __restrict__ V32,
    __bf16* __restrict__ Opart, float* __restrict__ Mpart, float* __restrict__ Lpart)
{
  __shared__ __bf16 Ks[128 * 64];     // 16 KB, xor-swizzled 16B granules
  __shared__ __bf16 Vt[32][136];      // 8.5 KB, natural [d][l]
  __shared__ __bf16 Pt[4][16][136];   // 17.4 KB, per-wave P^T [q][l]
  const int tid  = threadIdx.x;
  const int wave = tid >> 6, lane = tid & 63;
  const int lrow = lane & 15, quad = lane >> 4;
  const int ls = blockIdx.x, bh = blockIdx.y;
  const int l0base = ls * 512;

  const __bf16* Kb0 = K64 + (size_t)bh * 4096 * 32;        // kc plane
  const __bf16* Kb1 = Kb0 + KPLANE;                         // kp plane
  const __bf16* Vb  = V32 + (size_t)bh * 4096 * 32;

  // Q fragments: 5 tiles of 16 q-rows per wave; serves as MFMA B operand.
  b8v qa0[5], qa1[5];
#pragma unroll
  for (int t = 0; t < 5; ++t) {
    const __bf16* Qb = Q64 + ((size_t)bh * 320 + wave * 80 + t * 16 + lrow) * 64;
    qa0[t] = *(const b8v*)(Qb + quad * 8);
    qa1[t] = *(const b8v*)(Qb + 32 + quad * 8);
  }

  // V staging map: thread (vs = d-octet, vrh = l-pair) loads rows 2vrh, 2vrh+1
  const int vs = tid & 3, vrh = tid >> 2;    // vrh 0..63

  auto loadKV = [&](uint4* kr, uint4* vv, int c) {
    int l0 = l0base + c * 128;
#pragma unroll
    for (int it = 0; it < 4; ++it) {
      int slot = it * 256 + tid, row = slot >> 3, gs = slot & 7;
      int g = gs ^ (row & 7);
      const __bf16* src = (g < 4)
          ? (Kb0 + (size_t)(l0 + row) * 32 + g * 8)
          : (Kb1 + (size_t)(l0 + row) * 32 + (g - 4) * 8);
      kr[it] = *(const uint4*)src;
    }
    vv[0] = *(const uint4*)(Vb + (size_t)(l0 + 2 * vrh) * 32 + vs * 8);
    vv[1] = *(const uint4*)(Vb + (size_t)(l0 + 2 * vrh + 1) * 32 + vs * 8);
  };
  auto stage = [&](const uint4* kr, const uint4* vv) {
#pragma unroll
    for (int it = 0; it < 4; ++it) {
      int slot = it * 256 + tid;
      *(uint4*)((char*)Ks + slot * 16) = kr[it];
    }
    __bf16 a[8], b[8];
    *(uint4*)a = vv[0]; *(uint4*)b = vv[1];
#pragma unroll
    for (int j = 0; j < 8; ++j) {
      __bf16 pr[2] = {a[j], b[j]};
      *(uint32_t*)&Vt[vs * 8 + j][2 * vrh] = *(const uint32_t*)pr;
    }
  };
  auto readKA = [&](int wr, int g) -> b8v {   // K[l=wr][c = g*8 .. +8]
    int gs = g ^ (wr & 7);
    return *(const b8v*)((const char*)Ks + wr * 128 + gs * 16);
  };

  float mst[5], lst[5];
  f4 oacc[5][2];
#pragma unroll
  for (int t = 0; t < 5; ++t) {
    mst[t] = -1e30f; lst[t] = 0.f;
    oacc[t][0] = f4{0.f, 0.f, 0.f, 0.f};
    oacc[t][1] = f4{0.f, 0.f, 0.f, 0.f};
  }

  auto compute = [&]() {
#pragma unroll
    for (int t = 0; t < 5; ++t) {
      // S^T tiles: row l = ct*16 + quad*4 + r, col q = lrow
      f4 sc[8];
#pragma unroll
      for (int ct = 0; ct < 8; ++ct) {
        b8v ka0 = readKA(ct * 16 + lrow, quad);
        b8v ka1 = readKA(ct * 16 + lrow, 4 + quad);
        f4 z = f4{0.f, 0.f, 0.f, 0.f};
        z = MFMA_BF16(ka0, qa0[t], z);
        z = MFMA_BF16(ka1, qa1[t], z);
        sc[ct] = z;
      }
      // softmax over l: in-lane (32 vals) + cross-quad (lane^16, lane^32)
      float mx = sc[0][0];
#pragma unroll
      for (int ct = 0; ct < 8; ++ct)
#pragma unroll
        for (int r = 0; r < 4; ++r) mx = fmaxf(mx, sc[ct][r]);
      mx = fmaxf(mx, __shfl_xor(mx, 16));
      mx = fmaxf(mx, __shfl_xor(mx, 32));
      float mnew = fmaxf(mst[t], mx);
      float alpha = __expf(mst[t] - mnew);
      mst[t] = mnew;
      float rsum = 0.f;
#pragma unroll
      for (int ct = 0; ct < 8; ++ct)
#pragma unroll
        for (int r = 0; r < 4; ++r) {
          sc[ct][r] = __expf(sc[ct][r] - mnew);
          rsum += sc[ct][r];
        }
      rsum += __shfl_xor(rsum, 16);
      rsum += __shfl_xor(rsum, 32);
      lst[t] = lst[t] * alpha + rsum;
#pragma unroll
      for (int c2 = 0; c2 < 2; ++c2)
#pragma unroll
        for (int r = 0; r < 4; ++r) oacc[t][c2][r] *= alpha;

      // P^T -> per-wave LDS [q=lrow][l]; b64 writes (4 consecutive l per reg)
#pragma unroll
      for (int ct = 0; ct < 8; ++ct) {
        __bf16 p4[4];
#pragma unroll
        for (int r = 0; r < 4; ++r) p4[r] = (__bf16)sc[ct][r];
        *(uint2*)&Pt[wave][lrow][ct * 16 + quad * 4] = *(const uint2*)p4;
      }
      // O^T += V^T P^T
#pragma unroll
      for (int kt = 0; kt < 4; ++kt) {
        b8v pb = *(const b8v*)&Pt[wave][lrow][kt * 32 + quad * 8];
#pragma unroll
        for (int c2 = 0; c2 < 2; ++c2) {
          b8v va = *(const b8v*)&Vt[c2 * 16 + lrow][kt * 32 + quad * 8];
          oacc[t][c2] = MFMA_BF16(va, pb, oacc[t][c2]);
        }
      }
    }
  };

  uint4 kA[4], vA[2], kB[4], vB[2];
  loadKV(kA, vA, 0);
  for (int c = 0; c < 4; c += 2) {
    __syncthreads();
    stage(kA, vA);
    loadKV(kB, vB, c + 1);           // prefetch, in flight across compute
    __syncthreads();
    compute();
    __syncthreads();
    stage(kB, vB);
    if (c + 2 < 4) loadKV(kA, vA, c + 2);
    __syncthreads();
    compute();
  }

  // epilogue: O^T[d][q] -> Opart[q][d] (b64 packed), m/l per q
  const size_t pbase = ((size_t)bh * 8 + ls) * 320;
#pragma unroll
  for (int t = 0; t < 5; ++t) {
    int q = wave * 80 + t * 16 + lrow;
    float inv = 1.0f / lst[t];
#pragma unroll
    for (int c2 = 0; c2 < 2; ++c2) {
      __bf16 o4[4];
#pragma unroll
      for (int r = 0; r < 4; ++r) o4[r] = (__bf16)(oacc[t][c2][r] * inv);
      *(uint2*)&Opart[(pbase + q) * 32 + c2 * 16 + quad * 4] = *(const uint2*)o4;
    }
    if (quad == 0) {
      Mpart[pbase + q] = mst[t];
      Lpart[pbase + q] = lst[t];
    }
  }
}

// ---------------------------------------------------------------------------
// Kernel C2: combine 8 L-split partials -> Obf[b][n][256].
__global__ __launch_bounds__(256) void attn_combine(
    const __bf16* __restrict__ Opart, const float* __restrict__ Mpart,
    const float* __restrict__ Lpart, __bf16* __restrict__ Obf)
{
  const int bh = blockIdx.y;
  const int idx = blockIdx.x * 256 + threadIdx.x;   // 0..10239
  const int q = idx >> 5, d = idx & 31;
  if (q >= 300) return;
  const size_t rb = (size_t)bh * 8 * 320 + q;
  float m[8];
#pragma unroll
  for (int j = 0; j < 8; ++j) m[j] = Mpart[rb + j * 320];
  float M = m[0];
#pragma unroll
  for (int j = 1; j < 8; ++j) M = fmaxf(M, m[j]);
  float S = 0.f, o = 0.f;
#pragma unroll
  for (int j = 0; j < 8; ++j) {
    float w = Lpart[rb + j * 320] * __expf(m[j] - M);
    S += w;
    o += w * (float)Opart[(rb + j * 320) * 32 + d];
  }
  int b = bh >> 3, h = bh & 7;
  Obf[((size_t)b * 300 + q) * 256 + h * 32 + d] = (__bf16)(o / S);
}

// ---------------------------------------------------------------------------
// Kernel D: out = identity + Obf @ W_o^T + b_o (unchanged).
__global__ __launch_bounds__(256) void out_proj_gemm(
    const __bf16* __restrict__ Obf, const float* __restrict__ W_o,
    const float* __restrict__ b_o, const float* __restrict__ query,
    float* __restrict__ out)
{
  __shared__ __bf16 Ws[256][72];
  const int tid  = threadIdx.x;
  const int wave = tid >> 6, lane = tid & 63;
  const int lrow = lane & 15, quad = lane >> 4;
  const int r0 = blockIdx.x * 64;

  f4 acc[16];
#pragma unroll
  for (int i = 0; i < 16; ++i) acc[i] = f4{0.f, 0.f, 0.f, 0.f};

  for (int kc0 = 0; kc0 < 256; kc0 += 64) {
#pragma unroll
    for (int it = 0; it < 16; ++it) {
      int idx = it * 256 + tid;
      int row = idx >> 4, c4 = idx & 15;
      float4 w = *(const float4*)(W_o + (size_t)row * 256 + kc0 + c4 * 4);
      __bf16* dp = &Ws[row][c4 * 4];
      dp[0] = (__bf16)w.x; dp[1] = (__bf16)w.y; dp[2] = (__bf16)w.z; dp[3] = (__bf16)w.w;
    }
    __syncthreads();
#pragma unroll
    for (int kk = 0; kk < 64; kk += 32) {
      b8v a = *(const b8v*)(Obf + (size_t)(r0 + wave * 16 + lrow) * 256 + kc0 + kk + quad * 8);
#pragma unroll
      for (int ct = 0; ct < 16; ++ct) {
        b8v bf = *(const b8v*)&Ws[ct * 16 + lrow][kk + quad * 8];
        acc[ct] = MFMA_BF16(a, bf, acc[ct]);
      }
    }
    __syncthreads();
  }
#pragma unroll
  for (int ct = 0; ct < 16; ++ct) {
    int col = ct * 16 + lrow;
    float bo = b_o[col];
#pragma unroll
    for (int r = 0; r < 4; ++r) {
      int row = r0 + wave * 16 + quad * 4 + r;
      int bb = row / 300, n = row % 300;
      size_t oaddr = ((size_t)n * 16 + bb) * 256 + col;
      out[oaddr] = acc[ct][r] + bo + query[oaddr];
    }
  }
}

// ---------------------------------------------------------------------------
extern "C" void kernel_launch(void* const* d_in, const int* in_sizes, int n_in,
                              void* d_out, int out_size, void* d_ws, size_t ws_size,
                              hipStream_t stream) {
  (void)in_sizes; (void)n_in; (void)out_size; (void)ws_size;
  const float* query      = (const float*)d_in[0];
  const float* key        = (const float*)d_in[1];
  const float* value      = (const float*)d_in[2];
  const float* query_pos  = (const float*)d_in[3];
  const float* key_pos    = (const float*)d_in[4];
  const float* query_sine = (const float*)d_in[5];
  const float* W_qc = (const float*)d_in[6];  const float* b_qc = (const float*)d_in[7];
  const float* W_qp = (const float*)d_in[8];  const float* b_qp = (const float*)d_in[9];
  const float* W_qs = (const float*)d_in[10]; const float* b_qs = (const float*)d_in[11];
  const float* W_kc = (const float*)d_in[12]; const float* b_kc = (const float*)d_in[13];
  const float* W_kp = (const float*)d_in[14]; const float* b_kp = (const float*)d_in[15];
  const float* W_v  = (const float*)d_in[16]; const float* b_v  = (const float*)d_in[17];
  const float* W_o  = (const float*)d_in[18]; const float* b_o  = (const float*)d_in[19];
  float* out = (float*)d_out;

  char* ws = (char*)d_ws;
  constexpr size_t K64_BYTES = (size_t)128 * 4096 * 64 * 2;  // 64 MiB (2 planes of 32)
  constexpr size_t V32_BYTES = (size_t)128 * 4096 * 32 * 2;  // 32 MiB
  constexpr size_t Q64_BYTES = (size_t)128 * 320 * 64 * 2;   //  5 MiB
  constexpr size_t OBF_BYTES = (size_t)16 * 300 * 256 * 2;   //  2.34 MiB
  constexpr size_t WBF_BYTES = (size_t)3 * 256 * 256 * 2;    //  0.375 MiB
  constexpr size_t OPART_BYTES = (size_t)128 * 8 * 320 * 32 * 2;  // 20 MiB
  constexpr size_t MPART_BYTES = (size_t)128 * 8 * 320 * 4;       // 1.25 MiB
  __bf16* K64 = (__bf16*)ws;
  __bf16* V32 = (__bf16*)(ws + K64_BYTES);
  __bf16* Q64 = (__bf16*)(ws + K64_BYTES + V32_BYTES);
  __bf16* Obf = (__bf16*)(ws + K64_BYTES + V32_BYTES + Q64_BYTES);
  __bf16* Wbf = (__bf16*)(ws + K64_BYTES + V32_BYTES + Q64_BYTES + OBF_BYTES);
  char*  pbase = ws + K64_BYTES + V32_BYTES + Q64_BYTES + OBF_BYTES + WBF_BYTES;
  __bf16* Opart = (__bf16*)pbase;
  float*  Mpart = (float*)(pbase + OPART_BYTES);
  float*  Lpart = (float*)(pbase + OPART_BYTES + MPART_BYTES);

  hipLaunchKernelGGL(query_conv, dim3(267), dim3(256), 0, stream,
                     query, query_pos, query_sine, W_qc, b_qc, W_qp, b_qp, W_qs, b_qs, Q64,
                     W_kc, W_kp, W_v, Wbf);
  hipLaunchKernelGGL(key_side_gemm, dim3(512, 3), dim3(256), 0, stream,
                     key, key_pos, value, Wbf, b_kc, b_kp, b_v, K64, V32);
  hipLaunchKernelGGL(attn_part, dim3(8, 128), dim3(256), 0, stream,
                     Q64, K64, V32, Opart, Mpart, Lpart);
  hipLaunchKernelGGL(attn_combine, dim3(40, 128), dim3(256), 0, stream,
                     Opart, Mpart, Lpart, Obf);
  hipLaunchKernelGGL(out_proj_gemm, dim3(75), dim3(256), 0, stream,
                     Obf, W_o, b_o, query, out);
}

// Round 6
// 401.128 us; speedup vs baseline: 1.6334x; 1.1386x over previous
//
#include <hip/hip_runtime.h>
#include <cstdint>
#include <cstddef>

// MI355X / gfx950. bf16 MFMA implementation of ConditionalCrossAttention.
// score = (qc+qp)|(qc+qp+qs)  dot  kc|kp   (algebraic refold of the concat heads)
// R9: attn back to 4-way L-split (8-split regressed: 155 vs 130us). attn v9:
//  - K staged via global_load_lds into double-buffered Ks[2] (frees the 32-VGPR
//    kA/kB reg staging; counters showed ~170MB phantom (spill) writes).
//  - Vt double-buffered -> ONE barrier per chunk; next chunk's K gld_lds +
//    V global loads issued right after the barrier, in flight across compute
//    (m97 pattern: issue-after-barrier, drain-at-next-barrier).

typedef float  f4  __attribute__((ext_vector_type(4)));
typedef __bf16 b8v __attribute__((ext_vector_type(8)));

#define MFMA_BF16(a, b, c) __builtin_amdgcn_mfma_f32_16x16x32_bf16((a), (b), (c), 0, 0, 0)

#define GLD_LDS16(gp, lp)                                             \
  __builtin_amdgcn_global_load_lds(                                   \
      (const __attribute__((address_space(1))) void*)(gp),            \
      (__attribute__((address_space(3))) void*)(lp), 16, 0, 0)

// K64 plane stride: 128 bh * 4096 l * 32 d
#define KPLANE ((size_t)128 * 4096 * 32)

// ---------------------------------------------------------------------------
// Kernel A: key-side linears. Block = (l-chunk of 128 tokens, batch), p = matrix.
// (Verified R5 version, unchanged.)
__global__ __launch_bounds__(256, 2) void key_side_gemm(
    const float* __restrict__ key, const float* __restrict__ key_pos,
    const float* __restrict__ value, const __bf16* __restrict__ Wbf,
    const float* __restrict__ b_kc, const float* __restrict__ b_kp,
    const float* __restrict__ b_v,
    __bf16* __restrict__ K64, __bf16* __restrict__ V32)
{
  __shared__ char smem[65536];   // 2 x 32KB W dbuf; reused as 64KB output tile
  const int tid  = threadIdx.x;
  const int wave = tid >> 6, lane = tid & 63;
  const int lrow = lane & 15, quad = lane >> 4;
  const int p  = blockIdx.y;
  const int lc = blockIdx.x >> 4;          // l-chunk 0..31
  const int batch = blockIdx.x & 15;       // batch 0..15
  const int l0 = lc * 128;
  const int rowbase = (wave & 1) * 64;     // 2x2 wave grid: 64 rows x 128 cols each
  const int colbase = (wave >> 1) * 128;

  const float* __restrict__ X = (p == 0) ? key : (p == 1) ? key_pos : value;
  const __bf16* __restrict__ Wb = Wbf + (size_t)p * 65536;
  const float* __restrict__ bias = (p == 0) ? b_kc : (p == 1) ? b_kp : b_v;

  auto stageW = [&](int buf, int kc) {
#pragma unroll
    for (int it = 0; it < 8; ++it) {
      int slot = it * 256 + tid;            // 2048 granules of 16B
      int wr = slot >> 3, gp = slot & 7;
      int g  = gp ^ (wr & 7);
      GLD_LDS16(Wb + (size_t)wr * 256 + kc + g * 8, smem + buf * 32768 + slot * 16);
    }
  };
  auto readB = [&](int buf, int ct, int kk4) -> b8v {   // kk4 = kk/8 (0 or 4)
    int wr = colbase + ct * 16 + lrow;
    int g  = (kk4 + quad) ^ (wr & 7);
    return *(const b8v*)(smem + buf * 32768 + wr * 128 + g * 16);
  };
  // X row for token l, batch b lives at X[(l*16 + b)*256 + c]
  auto loadA = [&](float4* x0, float4* x1, int kc) {
#pragma unroll
    for (int rt = 0; rt < 4; ++rt) {
      const float* xp = X + ((size_t)(l0 + rowbase + rt * 16 + lrow) * 16 + batch) * 256
                          + kc + quad * 8;
      x0[rt] = *(const float4*)xp;
      x1[rt] = *(const float4*)(xp + 4);
    }
  };
  auto mk = [&](float4 x0, float4 x1) -> b8v {
    b8v t;
    t[0] = (__bf16)x0.x; t[1] = (__bf16)x0.y; t[2] = (__bf16)x0.z; t[3] = (__bf16)x0.w;
    t[4] = (__bf16)x1.x; t[5] = (__bf16)x1.y; t[6] = (__bf16)x1.z; t[7] = (__bf16)x1.w;
    return t;
  };

  f4 acc[4][8];
#pragma unroll
  for (int i = 0; i < 4; ++i)
#pragma unroll
    for (int j = 0; j < 8; ++j) acc[i][j] = f4{0.f, 0.f, 0.f, 0.f};

  float4 c0[4], c1[4], d0[4], d1[4];
  loadA(c0, c1, 0);
  stageW(0, 0);
  __syncthreads();

  for (int s = 0; s < 4; ++s) {
    const int kc0 = s * 64, buf = s & 1;
    loadA(d0, d1, kc0 + 32);
    if (s < 3) stageW(buf ^ 1, kc0 + 64);

    b8v a[4];
#pragma unroll
    for (int rt = 0; rt < 4; ++rt) a[rt] = mk(c0[rt], c1[rt]);
#pragma unroll
    for (int ct = 0; ct < 8; ++ct) {
      b8v bfr = readB(buf, ct, 0);
#pragma unroll
      for (int rt = 0; rt < 4; ++rt) acc[rt][ct] = MFMA_BF16(a[rt], bfr, acc[rt][ct]);
    }

    if (s < 3) loadA(c0, c1, kc0 + 64);

#pragma unroll
    for (int rt = 0; rt < 4; ++rt) a[rt] = mk(d0[rt], d1[rt]);
#pragma unroll
    for (int ct = 0; ct < 8; ++ct) {
      b8v bfr = readB(buf, ct, 4);
#pragma unroll
      for (int rt = 0; rt < 4; ++rt) acc[rt][ct] = MFMA_BF16(a[rt], bfr, acc[rt][ct]);
    }
    __syncthreads();
  }

  // epilogue: acc -> swizzled LDS tile [128][256] bf16 -> contiguous stores.
  __bf16* Os = (__bf16*)smem;
#pragma unroll
  for (int ct = 0; ct < 8; ++ct) {
    int col = colbase + ct * 16 + lrow;
    float bv = bias[col];
    int cg = col >> 3, cr = col & 7;
#pragma unroll
    for (int rt = 0; rt < 4; ++rt)
#pragma unroll
      for (int r = 0; r < 4; ++r) {
        int row = rowbase + rt * 16 + quad * 4 + r;
        int g = cg ^ ((row ^ (row >> 3)) & 7);
        Os[row * 256 + g * 8 + cr] = (__bf16)(acc[rt][ct][r] + bv);
      }
  }
  __syncthreads();
  // stores: per h, 128 consecutive rows of 32 bf16 (64 B) -> contiguous 8 KB runs
#pragma unroll
  for (int it = 0; it < 16; ++it) {
    int h   = it >> 1;
    int row = (it & 1) * 64 + (tid >> 2);
    int seg = tid & 3;
    int g = (h * 4 + seg) ^ ((row ^ (row >> 3)) & 7);
    uint4 v = *(const uint4*)(Os + row * 256 + g * 8);
    size_t rowidx = ((size_t)(batch * 8 + h) * 4096) + l0 + row;
    if (p == 2) *(uint4*)(V32 + rowidx * 32 + seg * 8) = v;
    else        *(uint4*)(K64 + (size_t)p * KPLANE + rowidx * 32 + seg * 8) = v;
  }
}

// ---------------------------------------------------------------------------
// Kernel B: query-side projections + (blocks >= 75) the W_k*/W_v fp32->bf16
// conversion. (Unchanged.)
__global__ __launch_bounds__(256) void query_conv(
    const float* __restrict__ query, const float* __restrict__ query_pos,
    const float* __restrict__ query_sine,
    const float* __restrict__ W_qc, const float* __restrict__ b_qc,
    const float* __restrict__ W_qp, const float* __restrict__ b_qp,
    const float* __restrict__ W_qs, const float* __restrict__ b_qs,
    __bf16* __restrict__ Q64,
    const float* __restrict__ W_kc, const float* __restrict__ W_kp,
    const float* __restrict__ W_v, __bf16* __restrict__ Wbf)
{
  __shared__ __bf16 Ws[256][72];
  if (blockIdx.x >= 75) {
    int i = (blockIdx.x - 75) * 256 + threadIdx.x;   // 0 .. 49151
    int base = i * 4;
    int m = base >> 16;
    int off = base & 65535;
    const float* W = (m == 0) ? W_kc : (m == 1) ? W_kp : W_v;
    float4 v = *(const float4*)(W + off);
    __bf16 o[4];
    o[0] = (__bf16)v.x; o[1] = (__bf16)v.y; o[2] = (__bf16)v.z; o[3] = (__bf16)v.w;
    *(uint2*)(Wbf + (size_t)m * 65536 + off) = *(uint2*)o;
    return;
  }
  const int tid  = threadIdx.x;
  const int wave = tid >> 6, lane = tid & 63;
  const int lrow = lane & 15, quad = lane >> 4;
  const int r0 = blockIdx.x * 64;

  f4 acc[16];
#pragma unroll
  for (int i = 0; i < 16; ++i) acc[i] = f4{0.f, 0.f, 0.f, 0.f};

  for (int kc = 0; kc < 768; kc += 64) {
    const float* X; const float* W;
    if (kc < 256)      { X = query;      W = W_qc; }
    else if (kc < 512) { X = query_pos;  W = W_qp; }
    else               { X = query_sine; W = W_qs; }
    const int ko = kc & 255;
#pragma unroll
    for (int it = 0; it < 16; ++it) {
      int idx = it * 256 + tid;
      int row = idx >> 4, c4 = idx & 15;
      float4 w = *(const float4*)(W + (size_t)row * 256 + ko + c4 * 4);
      __bf16* dp = &Ws[row][c4 * 4];
      dp[0] = (__bf16)w.x; dp[1] = (__bf16)w.y; dp[2] = (__bf16)w.z; dp[3] = (__bf16)w.w;
    }
    __syncthreads();
#pragma unroll
    for (int kk = 0; kk < 64; kk += 32) {
      const float* xp = X + (size_t)(r0 + wave * 16 + lrow) * 256 + ko + kk + quad * 8;
      float4 x0 = *(const float4*)xp;
      float4 x1 = *(const float4*)(xp + 4);
      b8v a;
      a[0] = (__bf16)x0.x; a[1] = (__bf16)x0.y; a[2] = (__bf16)x0.z; a[3] = (__bf16)x0.w;
      a[4] = (__bf16)x1.x; a[5] = (__bf16)x1.y; a[6] = (__bf16)x1.z; a[7] = (__bf16)x1.w;
#pragma unroll
      for (int ct = 0; ct < 16; ++ct) {
        b8v bf = *(const b8v*)&Ws[ct * 16 + lrow][kk + quad * 8];
        acc[ct] = MFMA_BF16(a, bf, acc[ct]);
      }
    }
    __syncthreads();
    if (kc == 448) {
#pragma unroll
      for (int ct = 0; ct < 16; ++ct) {
        int col = ct * 16 + lrow;
        float bsum = b_qc[col] + b_qp[col];
        int h = col >> 5, d = col & 31;
#pragma unroll
        for (int r = 0; r < 4; ++r) {
          int row = r0 + wave * 16 + quad * 4 + r;
          int n = row >> 4, bb = row & 15;
          Q64[((size_t)(bb * 8 + h) * 320 + n) * 64 + d] = (__bf16)((acc[ct][r] + bsum) * 0.125f);
        }
      }
    }
  }
#pragma unroll
  for (int ct = 0; ct < 16; ++ct) {
    int col = ct * 16 + lrow;
    float bsum = b_qc[col] + b_qp[col] + b_qs[col];
    int h = col >> 5, d = col & 31;
#pragma unroll
    for (int r = 0; r < 4; ++r) {
      int row = r0 + wave * 16 + quad * 4 + r;
      int n = row >> 4, bb = row & 15;
      Q64[((size_t)(bb * 8 + h) * 320 + n) * 64 + 32 + d] = (__bf16)((acc[ct][r] + bsum) * 0.125f);
    }
  }
}

// ---------------------------------------------------------------------------
// Kernel C v9: flash attention, 4-way L-split, S^T orientation.
// Grid (4 ls, 128 bh), 256 threads. 8 chunks of 128 tokens, ONE barrier/chunk:
//   stageV(cur) ; barrier ; issue gld_lds K(c+1)->Ks[nxt] + V(c+1) loads ;
//   compute(cur)    (loads stay in flight across compute, drained next barrier)
__global__ __launch_bounds__(256, 2) void attn_part(
    const __bf16* __restrict__ Q64, const __bf16* __restrict__ K64,
    const __bf16* __restrict__ V32,
    __bf16* __restrict__ Opart, float* __restrict__ Mpart, float* __restrict__ Lpart)
{
  __shared__ __bf16 Ks[2][128 * 64];  // 32 KB, xor-swizzled 16B granules, dbuf
  __shared__ __bf16 Vt[2][32][136];   // 17.4 KB, natural [d][l], dbuf
  __shared__ __bf16 Pt[4][16][136];   // 17.4 KB, per-wave P^T [q][l]
  const int tid  = threadIdx.x;
  const int wave = tid >> 6, lane = tid & 63;
  const int lrow = lane & 15, quad = lane >> 4;
  const int ls = blockIdx.x, bh = blockIdx.y;
  const int l0base = ls * 1024;

  const __bf16* Kb0 = K64 + (size_t)bh * 4096 * 32;        // kc plane
  const __bf16* Kb1 = Kb0 + KPLANE;                         // kp plane
  const __bf16* Vb  = V32 + (size_t)bh * 4096 * 32;

  // Q fragments: 5 tiles of 16 q-rows per wave; serves as MFMA B operand.
  b8v qa0[5], qa1[5];
#pragma unroll
  for (int t = 0; t < 5; ++t) {
    const __bf16* Qb = Q64 + ((size_t)bh * 320 + wave * 80 + t * 16 + lrow) * 64;
    qa0[t] = *(const b8v*)(Qb + quad * 8);
    qa1[t] = *(const b8v*)(Qb + 32 + quad * 8);
  }

  // V staging map: thread (vs = d-octet, vrh = l-pair) loads rows 2vrh, 2vrh+1
  const int vs = tid & 3, vrh = tid >> 2;    // vrh 0..63

  // K staging: global_load_lds, pre-swizzled per-lane global source, linear LDS
  auto issueK = [&](int buf, int c) {
    int l0 = l0base + c * 128;
#pragma unroll
    for (int it = 0; it < 4; ++it) {
      int slot = it * 256 + tid, row = slot >> 3, gs = slot & 7;
      int g = gs ^ (row & 7);
      const __bf16* src = (g < 4)
          ? (Kb0 + (size_t)(l0 + row) * 32 + g * 8)
          : (Kb1 + (size_t)(l0 + row) * 32 + (g - 4) * 8);
      GLD_LDS16(src, (char*)&Ks[buf][0] + slot * 16);
    }
  };
  auto loadV = [&](uint4* vv, int c) {
    int l0 = l0base + c * 128;
    vv[0] = *(const uint4*)(Vb + (size_t)(l0 + 2 * vrh) * 32 + vs * 8);
    vv[1] = *(const uint4*)(Vb + (size_t)(l0 + 2 * vrh + 1) * 32 + vs * 8);
  };
  auto stageV = [&](int buf, const uint4* vv) {
    __bf16 a[8], b[8];
    *(uint4*)a = vv[0]; *(uint4*)b = vv[1];
#pragma unroll
    for (int j = 0; j < 8; ++j) {
      __bf16 pr[2] = {a[j], b[j]};
      *(uint32_t*)&Vt[buf][vs * 8 + j][2 * vrh] = *(const uint32_t*)pr;
    }
  };
  auto readKA = [&](int buf, int wr, int g) -> b8v {   // K[l=wr][c = g*8 .. +8]
    int gs = g ^ (wr & 7);
    return *(const b8v*)((const char*)&Ks[buf][0] + wr * 128 + gs * 16);
  };

  float mst[5], lst[5];
  f4 oacc[5][2];
#pragma unroll
  for (int t = 0; t < 5; ++t) {
    mst[t] = -1e30f; lst[t] = 0.f;
    oacc[t][0] = f4{0.f, 0.f, 0.f, 0.f};
    oacc[t][1] = f4{0.f, 0.f, 0.f, 0.f};
  }

  auto compute = [&](int buf) {
#pragma unroll
    for (int t = 0; t < 5; ++t) {
      // S^T tiles: row l = ct*16 + quad*4 + r, col q = lrow
      f4 sc[8];
#pragma unroll
      for (int ct = 0; ct < 8; ++ct) {
        b8v ka0 = readKA(buf, ct * 16 + lrow, quad);
        b8v ka1 = readKA(buf, ct * 16 + lrow, 4 + quad);
        f4 z = f4{0.f, 0.f, 0.f, 0.f};
        z = MFMA_BF16(ka0, qa0[t], z);
        z = MFMA_BF16(ka1, qa1[t], z);
        sc[ct] = z;
      }
      // softmax over l: in-lane (32 vals) + cross-quad (lane^16, lane^32)
      float mx = sc[0][0];
#pragma unroll
      for (int ct = 0; ct < 8; ++ct)
#pragma unroll
        for (int r = 0; r < 4; ++r) mx = fmaxf(mx, sc[ct][r]);
      mx = fmaxf(mx, __shfl_xor(mx, 16));
      mx = fmaxf(mx, __shfl_xor(mx, 32));
      float mnew = fmaxf(mst[t], mx);
      float alpha = __expf(mst[t] - mnew);
      mst[t] = mnew;
      float rsum = 0.f;
#pragma unroll
      for (int ct = 0; ct < 8; ++ct)
#pragma unroll
        for (int r = 0; r < 4; ++r) {
          sc[ct][r] = __expf(sc[ct][r] - mnew);
          rsum += sc[ct][r];
        }
      rsum += __shfl_xor(rsum, 16);
      rsum += __shfl_xor(rsum, 32);
      lst[t] = lst[t] * alpha + rsum;
#pragma unroll
      for (int c2 = 0; c2 < 2; ++c2)
#pragma unroll
        for (int r = 0; r < 4; ++r) oacc[t][c2][r] *= alpha;

      // P^T -> per-wave LDS [q=lrow][l]; b64 writes (4 consecutive l per reg)
#pragma unroll
      for (int ct = 0; ct < 8; ++ct) {
        __bf16 p4[4];
#pragma unroll
        for (int r = 0; r < 4; ++r) p4[r] = (__bf16)sc[ct][r];
        *(uint2*)&Pt[wave][lrow][ct * 16 + quad * 4] = *(const uint2*)p4;
      }
      // O^T += V^T P^T
#pragma unroll
      for (int kt = 0; kt < 4; ++kt) {
        b8v pb = *(const b8v*)&Pt[wave][lrow][kt * 32 + quad * 8];
#pragma unroll
        for (int c2 = 0; c2 < 2; ++c2) {
          b8v va = *(const b8v*)&Vt[buf][c2 * 16 + lrow][kt * 32 + quad * 8];
          oacc[t][c2] = MFMA_BF16(va, pb, oacc[t][c2]);
        }
      }
    }
  };

  // ---- main loop: 8 chunks, one barrier per chunk ----
  uint4 vv[2];
  issueK(0, 0);
  loadV(vv, 0);
  for (int c = 0; c < 8; ++c) {
    const int cur = c & 1;
    stageV(cur, vv);               // V(c) regs -> Vt[cur] (vmcnt wait auto)
    __syncthreads();               // drains gld K(c)->Ks[cur]; Vt[cur] visible
    if (c + 1 < 8) {
      issueK(cur ^ 1, c + 1);      // in flight across compute
      loadV(vv, c + 1);            // in flight across compute
    }
    compute(cur);
  }

  // epilogue: O^T[d][q] -> Opart[q][d] (b64 packed), m/l per q
  const size_t pbase = ((size_t)bh * 4 + ls) * 320;
#pragma unroll
  for (int t = 0; t < 5; ++t) {
    int q = wave * 80 + t * 16 + lrow;
    float inv = 1.0f / lst[t];
#pragma unroll
    for (int c2 = 0; c2 < 2; ++c2) {
      __bf16 o4[4];
#pragma unroll
      for (int r = 0; r < 4; ++r) o4[r] = (__bf16)(oacc[t][c2][r] * inv);
      *(uint2*)&Opart[(pbase + q) * 32 + c2 * 16 + quad * 4] = *(const uint2*)o4;
    }
    if (quad == 0) {
      Mpart[pbase + q] = mst[t];
      Lpart[pbase + q] = lst[t];
    }
  }
}

// ---------------------------------------------------------------------------
// Kernel C2: combine 4 L-split partials -> Obf[b][n][256].
__global__ __launch_bounds__(256) void attn_combine(
    const __bf16* __restrict__ Opart, const float* __restrict__ Mpart,
    const float* __restrict__ Lpart, __bf16* __restrict__ Obf)
{
  const int bh = blockIdx.y;
  const int idx = blockIdx.x * 256 + threadIdx.x;   // 0..10239
  const int q = idx >> 5, d = idx & 31;
  if (q >= 300) return;
  const size_t rb = ((size_t)bh * 4) * 320 + q;
  float m0 = Mpart[rb], m1 = Mpart[rb + 320], m2 = Mpart[rb + 640], m3 = Mpart[rb + 960];
  float M = fmaxf(fmaxf(m0, m1), fmaxf(m2, m3));
  float w0 = Lpart[rb]       * __expf(m0 - M);
  float w1 = Lpart[rb + 320] * __expf(m1 - M);
  float w2 = Lpart[rb + 640] * __expf(m2 - M);
  float w3 = Lpart[rb + 960] * __expf(m3 - M);
  float S = w0 + w1 + w2 + w3;
  float o = w0 * (float)Opart[rb * 32 + d]
          + w1 * (float)Opart[(rb + 320) * 32 + d]
          + w2 * (float)Opart[(rb + 640) * 32 + d]
          + w3 * (float)Opart[(rb + 960) * 32 + d];
  int b = bh >> 3, h = bh & 7;
  Obf[((size_t)b * 300 + q) * 256 + h * 32 + d] = (__bf16)(o / S);
}

// ---------------------------------------------------------------------------
// Kernel D: out = identity + Obf @ W_o^T + b_o (unchanged).
__global__ __launch_bounds__(256) void out_proj_gemm(
    const __bf16* __restrict__ Obf, const float* __restrict__ W_o,
    const float* __restrict__ b_o, const float* __restrict__ query,
    float* __restrict__ out)
{
  __shared__ __bf16 Ws[256][72];
  const int tid  = threadIdx.x;
  const int wave = tid >> 6, lane = tid & 63;
  const int lrow = lane & 15, quad = lane >> 4;
  const int r0 = blockIdx.x * 64;

  f4 acc[16];
#pragma unroll
  for (int i = 0; i < 16; ++i) acc[i] = f4{0.f, 0.f, 0.f, 0.f};

  for (int kc0 = 0; kc0 < 256; kc0 += 64) {
#pragma unroll
    for (int it = 0; it < 16; ++it) {
      int idx = it * 256 + tid;
      int row = idx >> 4, c4 = idx & 15;
      float4 w = *(const float4*)(W_o + (size_t)row * 256 + kc0 + c4 * 4);
      __bf16* dp = &Ws[row][c4 * 4];
      dp[0] = (__bf16)w.x; dp[1] = (__bf16)w.y; dp[2] = (__bf16)w.z; dp[3] = (__bf16)w.w;
    }
    __syncthreads();
#pragma unroll
    for (int kk = 0; kk < 64; kk += 32) {
      b8v a = *(const b8v*)(Obf + (size_t)(r0 + wave * 16 + lrow) * 256 + kc0 + kk + quad * 8);
#pragma unroll
      for (int ct = 0; ct < 16; ++ct) {
        b8v bf = *(const b8v*)&Ws[ct * 16 + lrow][kk + quad * 8];
        acc[ct] = MFMA_BF16(a, bf, acc[ct]);
      }
    }
    __syncthreads();
  }
#pragma unroll
  for (int ct = 0; ct < 16; ++ct) {
    int col = ct * 16 + lrow;
    float bo = b_o[col];
#pragma unroll
    for (int r = 0; r < 4; ++r) {
      int row = r0 + wave * 16 + quad * 4 + r;
      int bb = row / 300, n = row % 300;
      size_t oaddr = ((size_t)n * 16 + bb) * 256 + col;
      out[oaddr] = acc[ct][r] + bo + query[oaddr];
    }
  }
}

// ---------------------------------------------------------------------------
extern "C" void kernel_launch(void* const* d_in, const int* in_sizes, int n_in,
                              void* d_out, int out_size, void* d_ws, size_t ws_size,
                              hipStream_t stream) {
  (void)in_sizes; (void)n_in; (void)out_size; (void)ws_size;
  const float* query      = (const float*)d_in[0];
  const float* key        = (const float*)d_in[1];
  const float* value      = (const float*)d_in[2];
  const float* query_pos  = (const float*)d_in[3];
  const float* key_pos    = (const float*)d_in[4];
  const float* query_sine = (const float*)d_in[5];
  const float* W_qc = (const float*)d_in[6];  const float* b_qc = (const float*)d_in[7];
  const float* W_qp = (const float*)d_in[8];  const float* b_qp = (const float*)d_in[9];
  const float* W_qs = (const float*)d_in[10]; const float* b_qs = (const float*)d_in[11];
  const float* W_kc = (const float*)d_in[12]; const float* b_kc = (const float*)d_in[13];
  const float* W_kp = (const float*)d_in[14]; const float* b_kp = (const float*)d_in[15];
  const float* W_v  = (const float*)d_in[16]; const float* b_v  = (const float*)d_in[17];
  const float* W_o  = (const float*)d_in[18]; const float* b_o  = (const float*)d_in[19];
  float* out = (float*)d_out;

  char* ws = (char*)d_ws;
  constexpr size_t K64_BYTES = (size_t)128 * 4096 * 64 * 2;  // 64 MiB (2 planes of 32)
  constexpr size_t V32_BYTES = (size_t)128 * 4096 * 32 * 2;  // 32 MiB
  constexpr size_t Q64_BYTES = (size_t)128 * 320 * 64 * 2;   //  5 MiB
  constexpr size_t OBF_BYTES = (size_t)16 * 300 * 256 * 2;   //  2.34 MiB
  constexpr size_t WBF_BYTES = (size_t)3 * 256 * 256 * 2;    //  0.375 MiB
  constexpr size_t OPART_BYTES = (size_t)128 * 4 * 320 * 32 * 2;  // 10.49 MB
  constexpr size_t MPART_BYTES = (size_t)128 * 4 * 320 * 4;       // 0.655 MB
  __bf16* K64 = (__bf16*)ws;
  __bf16* V32 = (__bf16*)(ws + K64_BYTES);
  __bf16* Q64 = (__bf16*)(ws + K64_BYTES + V32_BYTES);
  __bf16* Obf = (__bf16*)(ws + K64_BYTES + V32_BYTES + Q64_BYTES);
  __bf16* Wbf = (__bf16*)(ws + K64_BYTES + V32_BYTES + Q64_BYTES + OBF_BYTES);
  char*  pbase = ws + K64_BYTES + V32_BYTES + Q64_BYTES + OBF_BYTES + WBF_BYTES;
  __bf16* Opart = (__bf16*)pbase;
  float*  Mpart = (float*)(pbase + OPART_BYTES);
  float*  Lpart = (float*)(pbase + OPART_BYTES + MPART_BYTES);

  hipLaunchKernelGGL(query_conv, dim3(267), dim3(256), 0, stream,
                     query, query_pos, query_sine, W_qc, b_qc, W_qp, b_qp, W_qs, b_qs, Q64,
                     W_kc, W_kp, W_v, Wbf);
  hipLaunchKernelGGL(key_side_gemm, dim3(512, 3), dim3(256), 0, stream,
                     key, key_pos, value, Wbf, b_kc, b_kp, b_v, K64, V32);
  hipLaunchKernelGGL(attn_part, dim3(4, 128), dim3(256), 0, stream,
                     Q64, K64, V32, Opart, Mpart, Lpart);
  hipLaunchKernelGGL(attn_combine, dim3(40, 128), dim3(256), 0, stream,
                     Opart, Mpart, Lpart, Obf);
  hipLaunchKernelGGL(out_proj_gemm, dim3(75), dim3(256), 0, stream,
                     Obf, W_o, b_o, query, out);
}